// Round 16
// baseline (604.694 us; speedup 1.0000x reference)
//
#include <hip/hip_runtime.h>
#include <hip/hip_bf16.h>
#include <math.h>

#define NH 8
#define DH 32
#define DIM 256
#define SEQ 2048
#define BATCH 4
#define NB 512            // SEQ / C
#define QKS 512           // q|k packed f32 row stride
#define VGS 320           // v|g packed bf16 row stride: 256 v | 24 g | 40 pad
#define SCALE 0.17677669529663687f  // DH^-0.5

typedef short short8v __attribute__((ext_vector_type(8)));
typedef float float4v __attribute__((ext_vector_type(4)));

__device__ __forceinline__ float sigmoidf_(float x){ return 1.f/(1.f+__expf(-x)); }
__device__ __forceinline__ ushort f2bf(float f){
  uint b = __float_as_uint(f);
  return (ushort)((b + 0x7fffu + ((b>>16)&1u)) >> 16);   // RNE
}
__device__ __forceinline__ float bf2f(ushort u){ return __uint_as_float(((uint)u)<<16); }
__device__ __forceinline__ float bflo(uint u){ return __uint_as_float(u<<16); }
__device__ __forceinline__ float bfhi(uint u){ return __uint_as_float(u & 0xffff0000u); }
__device__ __forceinline__ uint pk2(float a, float b){ return (uint)f2bf(a) | ((uint)f2bf(b)<<16); }
__device__ __forceinline__ void bfu4_to_f32(uint4 u, float* f){
  f[0]=bflo(u.x); f[1]=bfhi(u.x);
  f[2]=bflo(u.y); f[3]=bfhi(u.y);
  f[4]=bflo(u.z); f[5]=bfhi(u.z);
  f[6]=bflo(u.w); f[7]=bfhi(u.w);
}
__device__ __forceinline__ void bfu2_to_f32(uint2 u, float* f){
  f[0]=bflo(u.x); f[1]=bfhi(u.x);
  f[2]=bflo(u.y); f[3]=bfhi(u.y);
}

// ---------------- copy (residual stream init) ----------------
__global__ void copy_f32(const float* __restrict__ in, float* __restrict__ out, int n4){
  int i = blockIdx.x*blockDim.x + threadIdx.x;
  if (i < n4) ((float4*)out)[i] = ((const float4*)in)[i];
}

// ---------------- weight packers ----------------
__global__ void build_wqk(const float* __restrict__ Wq, const float* __restrict__ Wk, float* __restrict__ out){
  int i = blockIdx.x*256 + threadIdx.x;          // 4*256*512
  if (i >= 4*256*QKS) return;
  int col = i & 511, rk = (i>>9)&255, l = i>>17;
  out[i] = (col < 256) ? Wq[((size_t)l*256+rk)*256+col] : Wk[((size_t)l*256+rk)*256+col-256];
}
__global__ void build_wvgT(const float* __restrict__ Wv, const float* __restrict__ Wg, ushort* __restrict__ out){
  int i = blockIdx.x*256 + threadIdx.x;          // 4*320*256 : out[l][n][k] = B[k][n]
  if (i >= 4*VGS*256) return;
  int k = i & 255, n = (i>>8)%VGS, l = i/(VGS*256);
  float v = 0.f;
  if      (n < 256) v = Wv[((size_t)l*256+k)*256+n];
  else if (n < 280) v = Wg[((size_t)l*256+k)*24 + (n-256)];
  out[i] = f2bf(v);
}
__global__ void build_wT(const float* __restrict__ in, ushort* __restrict__ out, int L, int K, int N){
  int i = blockIdx.x*256 + threadIdx.x;          // out[l][n][k] = in[l][k][n]
  if (i >= L*K*N) return;
  int k = i % K, n = (i/K) % N, l = i/(K*N);
  out[i] = f2bf(in[((size_t)l*K+k)*N+n]);
}

// ---------------- layernorm: one wave per row, dual f32+bf16 output ----------------
__global__ __launch_bounds__(256) void ln_k(const float* __restrict__ x, const float* __restrict__ g,
                                            const float* __restrict__ b, float* __restrict__ h,
                                            ushort* __restrict__ hb){
  int row  = blockIdx.x*4 + (threadIdx.x>>6);
  int lane = threadIdx.x & 63;
  int c = lane*4;
  const float* xr = x + (size_t)row*DIM + c;
  float4 v = *(const float4*)xr;
  float s = v.x+v.y+v.z+v.w;
  float q = v.x*v.x+v.y*v.y+v.z*v.z+v.w*v.w;
  #pragma unroll
  for (int off=32; off>0; off>>=1){ s += __shfl_xor(s, off); q += __shfl_xor(q, off); }
  float mean = s * (1.f/DIM);
  float var  = q * (1.f/DIM) - mean*mean;
  float rs = rsqrtf(var + 1e-5f);
  float4 gg = *(const float4*)(g + c);
  float4 bb = *(const float4*)(b + c);
  float4 o;
  o.x = (v.x-mean)*rs*gg.x + bb.x;
  o.y = (v.y-mean)*rs*gg.y + bb.y;
  o.z = (v.z-mean)*rs*gg.z + bb.z;
  o.w = (v.w-mean)*rs*gg.w + bb.w;
  *(float4*)(h + (size_t)row*DIM + c) = o;
  uint2 u;
  u.x = pk2(o.x, o.y);
  u.y = pk2(o.z, o.w);
  *(uint2*)&hb[(size_t)row*DIM + c] = u;
}

// ---------------- f32 GEMM (q|k path), guard-free, BK=32 ----------------
template<bool BIAS, bool LEAKY, bool ACC>
__global__ __launch_bounds__(256) void gemm_f32(const float* __restrict__ A, const float* __restrict__ B,
                                                const float* __restrict__ bias, float* __restrict__ C,
                                                int M, int N, int K){
  __shared__ float As[32][132];
  __shared__ float Bs[32][68];
  int tid = threadIdx.x;
  int m0 = blockIdx.x*128, n0 = blockIdx.y*64;
  int tx = tid & 15, ty = tid >> 4;
  int ar = tid >> 1;            // 0..127
  int ac = (tid & 1)*16;        // 0 or 16
  int bk = tid >> 3;            // 0..31
  int bn = (tid & 7)*8;         // 0..56
  const float* Ap = A + (size_t)(m0+ar)*K + ac;
  const float* Bp = B + (size_t)bk*N + n0 + bn;
  float4 apre[4], bpre[2];
  #pragma unroll
  for (int j=0;j<4;j++) apre[j] = *(const float4*)(Ap + 4*j);
  bpre[0] = *(const float4*)Bp;
  bpre[1] = *(const float4*)(Bp + 4);
  float acc[8][4];
  #pragma unroll
  for (int i=0;i<8;i++)
    #pragma unroll
    for (int j=0;j<4;j++) acc[i][j]=0.f;
  for (int k0=0; k0<K; k0+=32){
    #pragma unroll
    for (int j=0;j<4;j++){
      As[ac+4*j+0][ar]=apre[j].x; As[ac+4*j+1][ar]=apre[j].y;
      As[ac+4*j+2][ar]=apre[j].z; As[ac+4*j+3][ar]=apre[j].w;
    }
    *(float4*)&Bs[bk][bn]   = bpre[0];
    *(float4*)&Bs[bk][bn+4] = bpre[1];
    __syncthreads();
    if (k0 + 32 < K){
      #pragma unroll
      for (int j=0;j<4;j++) apre[j] = *(const float4*)(Ap + k0 + 32 + 4*j);
      bpre[0] = *(const float4*)(Bp + (size_t)(k0+32)*N);
      bpre[1] = *(const float4*)(Bp + (size_t)(k0+32)*N + 4);
    }
    #pragma unroll
    for (int kk=0;kk<32;kk++){
      float4 bv  = *(const float4*)&Bs[kk][tx*4];
      float4 av0 = *(const float4*)&As[kk][ty*8];
      float4 av1 = *(const float4*)&As[kk][ty*8+4];
      float av[8] = {av0.x,av0.y,av0.z,av0.w,av1.x,av1.y,av1.z,av1.w};
      float bw[4] = {bv.x,bv.y,bv.z,bv.w};
      #pragma unroll
      for (int i=0;i<8;i++)
        #pragma unroll
        for (int j=0;j<4;j++) acc[i][j] += av[i]*bw[j];
    }
    __syncthreads();
  }
  #pragma unroll
  for (int i=0;i<8;i++){
    int m = m0 + ty*8 + i;
    #pragma unroll
    for (int j=0;j<4;j++){
      int n = n0 + tx*4 + j;
      float val = acc[i][j];
      if (BIAS)  val += bias[n];
      if (LEAKY) val = val > 0.f ? val : 0.01f*val;
      float* cp = C + (size_t)m*N + n;
      if (ACC) val += *cp;
      *cp = val;
    }
  }
}

// ---------------- bf16 MFMA GEMM: C = act(A[M,K] @ Bt[N,K]^T + bias) ----------------
template<bool BIAS, bool LEAKY, bool ACC, bool OBF16>
__global__ __launch_bounds__(256) void gemm_bf16(const ushort* __restrict__ A, const ushort* __restrict__ Bt,
                                                 const float* __restrict__ bias, void* __restrict__ Cv,
                                                 int M, int N, int K){
  __shared__ ushort Al[128*64];
  __shared__ ushort Bl[64*64];
  int tid = threadIdx.x;
  int m0 = blockIdx.x*128, n0 = blockIdx.y*64;
  int w = tid>>6, lane = tid&63;
  int wm = w>>1, wn = w&1;
  float4v acc[4][2];
  #pragma unroll
  for (int i=0;i<4;i++)
    #pragma unroll
    for (int j=0;j<2;j++) acc[i][j] = (float4v){0.f,0.f,0.f,0.f};
  for (int k0=0; k0<K; k0+=64){
    #pragma unroll
    for (int i=0;i<4;i++){
      int id = tid + 256*i;
      int r = id>>3, c = id&7;
      *(uint4*)&Al[r*64 + ((c ^ (r&7))*8)] = *(const uint4*)&A[(size_t)(m0+r)*K + k0 + c*8];
    }
    #pragma unroll
    for (int i=0;i<2;i++){
      int id = tid + 256*i;
      int r = id>>3, c = id&7;
      *(uint4*)&Bl[r*64 + ((c ^ (r&7))*8)] = *(const uint4*)&Bt[(size_t)(n0+r)*K + k0 + c*8];
    }
    __syncthreads();
    #pragma unroll
    for (int kk=0; kk<2; ++kk){
      short8v a[4], bfr[2];
      #pragma unroll
      for (int mf=0; mf<4; mf++){
        int r = wm*64 + mf*16 + (lane&15);
        int c = (kk*4 + (lane>>4)) ^ (r&7);
        a[mf] = *(short8v*)&Al[r*64 + c*8];
      }
      #pragma unroll
      for (int nf=0; nf<2; nf++){
        int r = wn*32 + nf*16 + (lane&15);
        int c = (kk*4 + (lane>>4)) ^ (r&7);
        bfr[nf] = *(short8v*)&Bl[r*64 + c*8];
      }
      #pragma unroll
      for (int mf=0; mf<4; mf++)
        #pragma unroll
        for (int nf=0; nf<2; nf++)
          acc[mf][nf] = __builtin_amdgcn_mfma_f32_16x16x32_bf16(a[mf], bfr[nf], acc[mf][nf], 0, 0, 0);
    }
    __syncthreads();
  }
  #pragma unroll
  for (int nf=0; nf<2; nf++){
    int col = n0 + wn*32 + nf*16 + (lane&15);
    float bv = BIAS ? bias[col] : 0.f;
    #pragma unroll
    for (int mf=0; mf<4; mf++){
      #pragma unroll
      for (int r=0; r<4; r++){
        int row = m0 + wm*64 + mf*16 + (lane>>4)*4 + r;
        float vv = acc[mf][nf][r];
        if (BIAS) vv += bv;
        if (LEAKY) vv = vv > 0.f ? vv : 0.01f*vv;
        if (OBF16) ((ushort*)Cv)[(size_t)row*N + col] = f2bf(vv);
        else {
          float* C = (float*)Cv;
          if (ACC) vv += C[(size_t)row*N + col];
          C[(size_t)row*N + col] = vv;
        }
      }
    }
  }
}

// ---------------- mean-pool K/V blocks (C=4): kc [b][h][n][32] f32, vct [b][h][d][n] bf16 ----------------
__global__ void pool_k(const float* __restrict__ qk, const ushort* __restrict__ vg,
                       float* __restrict__ kc, ushort* __restrict__ vct){
  int i = blockIdx.x*256 + threadIdx.x;       // 0 .. B*H*NB*32-1
  if (i >= BATCH*NH*NB*DH) return;
  int d = i & 31, n = (i >> 5) & 511, h = (i >> 14) & 7, b = i >> 17;
  size_t kb = ((size_t)(b*SEQ + n*4))*QKS + 256 + h*DH + d;
  kc[i] = 0.25f*(qk[kb] + qk[kb+QKS] + qk[kb+2*QKS] + qk[kb+3*QKS]);
  size_t vb = ((size_t)(b*SEQ + n*4))*VGS + h*DH + d;
  float pv = 0.25f*(bf2f(vg[vb]) + bf2f(vg[vb+VGS]) + bf2f(vg[vb+2*VGS]) + bf2f(vg[vb+3*VGS]));
  vct[(((size_t)(b*NH + h))*DH + d)*NB + n] = f2bf(pv);   // transposed: MFMA-A-ready
}

// ---------------- fused NSA attention v11b: 8-wave phase 1, reg-direct phase 2 ----------------
// 32 groups x 64 tokens per (b,h). Grid 1024 x 512 threads (8 waves).
// Block e: hh=e&7 (XCD slot), b=(e>>3)&3, q=(e>>5)&7, r=e>>8;
//   g = {31-q, q, 23-q, 8+q}[r] -> bijective, per-CU weight ~constant, heavy first.
// Phase 1 per 64-n tile: stage kt f32 + vcT bf16 [d][n]; wave w scores CONTIGUOUS
//   rows [8w, 8w+8) (lane=token, EXACT grouped-4 f32 dot, argmax bitwise-preserved);
//   p->bf16 written as one b128 at Pl offset 8w == n_local (identity k-mapping on
//   BOTH MFMA operands — R15's strided rows permuted Pl's k-index vs vcT: the bug).
//   MFMA (waves 0-3): A=vcT (rows=d), B=Pl rows [16w,16w+16) -> lane owns token
//   w*16+(lane&15), d-set {4m..4m+3}u{16+4m..} (m=lane>>4); oc stays IN REGISTERS.
// Phase 2 (waves 0-3): token = g*64 + w*16 + (lane&15); 4 lanes (m) d-split; meta
//   combine over 8 splits (equal-score -> lower-n guard); cross-lane dots via
//   shfl_xor(16/32).
__global__ __launch_bounds__(512, 6) void nsa_attn(
    const float* __restrict__ qk, const ushort* __restrict__ vg,
    const float* __restrict__ kc, const ushort* __restrict__ vct,
    ushort* __restrict__ o)
{
  __shared__ float  kt[64*32];       // 8 KB f32 kc tile
  __shared__ ushort vcT[32*72];      // 4.5 KB bf16 Vc^T tile [d][n], pad 8
  __shared__ ushort Pl[64*72];       // 9 KB bf16 P tile [tok][n], pad 8
  __shared__ float4 meta[8*64];      // 8 KB (l, best, bestn, -)   -> 29.5 KB
  int e = blockIdx.x;
  int hh = e & 7;
  int b  = (e >> 3) & 3;
  int qq = (e >> 5) & 7;
  int r  = e >> 8;
  int g  = (r==0) ? (31-qq) : (r==1) ? qq : (r==2) ? (23-qq) : (8+qq);
  int tid = threadIdx.x;
  int w = tid >> 6, lane = tid & 63;
  const float*  kcg  = kc  + ((size_t)(b*NH + hh)*NB)*DH;
  const ushort* vctg = vct + ((size_t)(b*NH + hh)*DH)*NB;

  float4v acc0 = (float4v){0.f,0.f,0.f,0.f};
  float4v acc1 = (float4v){0.f,0.f,0.f,0.f};

  // ---- phase 1
  {
    int t = g*64 + lane;
    int own = t >> 2, nvis = (t+1) >> 2;
    int nmax = 16*(g+1);                  // block-uniform visibility bound
    float qv[32];
    {
      const float4* qr = (const float4*)(qk + ((size_t)b*SEQ + t)*QKS + hh*DH);
      #pragma unroll
      for (int d8=0; d8<8; d8++){
        float4 a4 = qr[d8];
        qv[4*d8]=a4.x; qv[4*d8+1]=a4.y; qv[4*d8+2]=a4.z; qv[4*d8+3]=a4.w;
      }
    }
    float l = 0.f, best = -1e30f;
    int bn1 = -1;

    int tiles = (g + 4) >> 2;             // ceil(16(g+1)/64)
    for (int ti=0; ti<tiles; ++ti){
      int base = ti*64;
      if (ti) __syncthreads();            // prev tile fully consumed
      {                                   // stage: kt 512xfloat4 (all threads), vcT 256xuint4
        const float4* sk = (const float4*)(kcg + (size_t)base*DH);
        ((float4*)kt)[tid] = sk[tid];
        if (tid < 256){
          int sd = tid >> 3, sn = (tid & 7)*8;
          *(uint4*)&vcT[sd*72 + sn] = *(const uint4*)&vctg[(size_t)sd*NB + base + sn];
        }
      }
      __syncthreads();
      // score phase: wave w owns CONTIGUOUS rows [8w, 8w+8) -> Pl k-index == n_local
      int jm = nmax - base - 8*w;         // uniform early exit past nvis_max
      jm = jm < 0 ? 0 : (jm > 8 ? 8 : jm);
      float ps[8];
      #pragma unroll
      for (int j=0;j<8;j++) ps[j]=0.f;
      for (int j=0; j<jm; ++j){
        int rr = 8*w + j;
        int n = base + rr;
        const float4* kp = (const float4*)&kt[rr*32];
        float s = 0.f;
        #pragma unroll
        for (int d8=0; d8<8; d8++){       // exact grouped-4 ordering: argmax-stable
          float4 k4 = kp[d8];
          s += qv[4*d8]*k4.x + qv[4*d8+1]*k4.y + qv[4*d8+2]*k4.z + qv[4*d8+3]*k4.w;
        }
        s *= SCALE;
        bool act = (n < nvis);
        if (act && n != own && s > best){ best = s; bn1 = n; }  // ascending n in-wave
        float p = act ? __expf(s) : 0.f;  // max-free: |s| small, exp safe
        l += p;
        ps[j] = p;
      }
      {                                   // P[lane][8w .. 8w+8) as 1x b128 (identity k-map)
        uint4 u0;
        u0.x = pk2(ps[0],ps[1]);  u0.y = pk2(ps[2],ps[3]);
        u0.z = pk2(ps[4],ps[5]);  u0.w = pk2(ps[6],ps[7]);
        *(uint4*)&Pl[lane*72 + w*8] = u0;
      }
      __syncthreads();                    // P complete
      // MFMA (waves 0-3): A=vcT rows d, B=Pl rows [16w,16w+16), K=64 via 2 ksteps
      if (w < 4){
        #pragma unroll
        for (int ks=0; ks<2; ++ks){
          short8v bfrag = *(short8v*)&Pl [(16*w + (lane&15))*72 + ks*32 + (lane>>4)*8];
          short8v a0    = *(short8v*)&vcT[(lane&15)*72          + ks*32 + (lane>>4)*8];
          short8v a1    = *(short8v*)&vcT[((lane&15)+16)*72     + ks*32 + (lane>>4)*8];
          acc0 = __builtin_amdgcn_mfma_f32_16x16x32_bf16(a0, bfrag, acc0, 0, 0, 0);
          acc1 = __builtin_amdgcn_mfma_f32_16x16x32_bf16(a1, bfrag, acc1, 0, 0, 0);
        }
      }
    }
    meta[w*64 + lane] = make_float4(l, best, __int_as_float(bn1), 0.f);
  }
  __syncthreads();

  // ---- phase 2 (waves 0-3): token = g*64 + w*16 + (lane&15); lane m=lane>>4 owns
  //      d-set {4m..4m+3} u {16+4m..16+4m+3}; oc comes straight from acc0/acc1.
  if (w < 4){
    int c = lane & 15, m = lane >> 4;
    int tokidx = w*16 + c;
    int t = g*64 + tokidx;
    int own = t >> 2, nvis = (t+1) >> 2;
    int dA = 4*m, dB = 16 + 4*m;
    float q8[8];
    {
      const float* qrow = qk + ((size_t)b*SEQ + t)*QKS + hh*DH;
      float4 a4 = *(const float4*)(qrow + dA);
      float4 b4 = *(const float4*)(qrow + dB);
      q8[0]=a4.x; q8[1]=a4.y; q8[2]=a4.z; q8[3]=a4.w;
      q8[4]=b4.x; q8[5]=b4.y; q8[6]=b4.z; q8[7]=b4.w;
    }
    float out8[8];
    #pragma unroll
    for (int j=0;j<4;j++){ out8[j] = acc0[j]; out8[4+j] = acc1[j]; }
    float ll = 0.f, bb = -1e30f;
    int bn = (own==0) ? 1 : 0;         // jax top_k fallback
    #pragma unroll
    for (int sp=0; sp<8; ++sp){
      float4 m4 = meta[sp*64 + tokidx];
      ll += m4.x;
      int mi = __float_as_int(m4.z);
      // interleaved splits: equal scores resolve to the lower n (mi>=0 excludes empties)
      if (m4.y > bb || (m4.y == bb && mi >= 0 && mi < bn)){ bb = m4.y; bn = mi; }
    }
    const ushort* gr = vg + ((size_t)b*SEQ + t)*VGS + 256;
    float g0 = sigmoidf_(bf2f(gr[hh])), g1 = sigmoidf_(bf2f(gr[8+hh])), g2 = sigmoidf_(bf2f(gr[16+hh]));
    float inv = (nvis > 0) ? g0/ll : 0.f;
    #pragma unroll
    for (int j=0;j<8;j++) out8[j] *= inv;

    // selection branch: own block + best block, causal token mask, d-split dots
    const float*  kb2 = qk + (size_t)b*SEQ*QKS + 256 + hh*DH;
    const ushort* vb2 = vg + (size_t)b*SEQ*VGS + hh*DH;
    float s2[8];
    float m2 = -1e30f;
    #pragma unroll
    for (int ki=0; ki<8; ++ki){
      int tt = (ki<4 ? own : bn)*4 + (ki&3);
      float s = -1e30f;
      if (tt <= t){                       // uniform across the 4 lanes of this token
        const float* kr = kb2 + (size_t)tt*QKS;
        float4 a4 = *(const float4*)(kr + dA);
        float4 c4 = *(const float4*)(kr + dB);
        float ps = q8[0]*a4.x + q8[1]*a4.y + q8[2]*a4.z + q8[3]*a4.w
                 + q8[4]*c4.x + q8[5]*c4.y + q8[6]*c4.z + q8[7]*c4.w;
        ps += __shfl_xor(ps, 16);
        ps += __shfl_xor(ps, 32);
        s = ps*SCALE;
        m2 = fmaxf(m2, s);
      }
      s2[ki] = s;
    }
    float l2 = 0.f;
    #pragma unroll
    for (int ki=0; ki<8; ++ki)
      if (s2[ki] > -1e29f) l2 += __expf(s2[ki] - m2);
    float inv2 = g1/l2;                   // l2 >= 1 (self token always visible)
    #pragma unroll
    for (int ki=0; ki<8; ++ki){
      int tt = (ki<4 ? own : bn)*4 + (ki&3);
      if (tt <= t){
        float pw = __expf(s2[ki] - m2) * inv2;
        float fA[4], fB[4];
        bfu2_to_f32(*(const uint2*)(vb2 + (size_t)tt*VGS + dA), fA);
        bfu2_to_f32(*(const uint2*)(vb2 + (size_t)tt*VGS + dB), fB);
        #pragma unroll
        for (int j=0;j<4;j++){ out8[j] += pw*fA[j]; out8[4+j] += pw*fB[j]; }
      }
    }

    // sliding window (W=2): tokens t-1, t
    int tp = (t>0) ? t-1 : 0;
    float sa, sb;
    {
      const float* ka = kb2 + (size_t)tp*QKS;
      const float* kb4= kb2 + (size_t)t *QKS;
      float4 a0 = *(const float4*)(ka + dA), a1 = *(const float4*)(ka + dB);
      float4 b0 = *(const float4*)(kb4 + dA), b1 = *(const float4*)(kb4 + dB);
      float pa_ = q8[0]*a0.x + q8[1]*a0.y + q8[2]*a0.z + q8[3]*a0.w
                + q8[4]*a1.x + q8[5]*a1.y + q8[6]*a1.z + q8[7]*a1.w;
      float pb_ = q8[0]*b0.x + q8[1]*b0.y + q8[2]*b0.z + q8[3]*b0.w
                + q8[4]*b1.x + q8[5]*b1.y + q8[6]*b1.z + q8[7]*b1.w;
      pa_ += __shfl_xor(pa_, 16); pa_ += __shfl_xor(pa_, 32);
      pb_ += __shfl_xor(pb_, 16); pb_ += __shfl_xor(pb_, 32);
      sa = pa_*SCALE; sb = pb_*SCALE;
    }
    float m3 = (t>0) ? fmaxf(sa, sb) : sb;
    float pa = (t>0) ? __expf(sa-m3) : 0.f;
    float pb = __expf(sb-m3);
    float inv3 = g2/(pa+pb);
    float va[4], vaB[4], vbv[4], vbB[4];
    bfu2_to_f32(*(const uint2*)(vb2 + (size_t)tp*VGS + dA), va);
    bfu2_to_f32(*(const uint2*)(vb2 + (size_t)tp*VGS + dB), vaB);
    bfu2_to_f32(*(const uint2*)(vb2 + (size_t)t *VGS + dA), vbv);
    bfu2_to_f32(*(const uint2*)(vb2 + (size_t)t *VGS + dB), vbB);
    ushort* orow = o + ((size_t)b*SEQ + t)*DIM + hh*DH;
    float rrA[4], rrB[4];
    #pragma unroll
    for (int j=0;j<4;j++){
      rrA[j] = out8[j]   + (pa*va[j]  + pb*vbv[j])*inv3;
      rrB[j] = out8[4+j] + (pa*vaB[j] + pb*vbB[j])*inv3;
    }
    uint2 uA, uB;
    uA.x = pk2(rrA[0], rrA[1]); uA.y = pk2(rrA[2], rrA[3]);
    uB.x = pk2(rrB[0], rrB[1]); uB.y = pk2(rrB[2], rrB[3]);
    *(uint2*)&orow[dA] = uA;
    *(uint2*)&orow[dB] = uB;
  }
}

extern "C" void kernel_launch(void* const* d_in, const int* in_sizes, int n_in,
                              void* d_out, int out_size, void* d_ws, size_t ws_size,
                              hipStream_t stream) {
  const float* x_in   = (const float*)d_in[0];
  const float* ln_a_g = (const float*)d_in[1];
  const float* ln_a_b = (const float*)d_in[2];
  const float* Wq     = (const float*)d_in[3];
  const float* Wk     = (const float*)d_in[4];
  const float* Wv     = (const float*)d_in[5];
  const float* Wg     = (const float*)d_in[6];
  const float* Wo     = (const float*)d_in[7];
  const float* ln_f_g = (const float*)d_in[8];
  const float* ln_f_b = (const float*)d_in[9];
  const float* W1     = (const float*)d_in[10];
  const float* b1     = (const float*)d_in[11];
  const float* W2     = (const float*)d_in[12];
  const float* b2     = (const float*)d_in[13];

  float* xout = (float*)d_out;             // running residual stream [8192][256] f32
  float* ws = (float*)d_ws;
  const size_t NTOK = (size_t)BATCH*SEQ;   // 8192
  float* h    = ws;                                    // [8192][256] f32
  float* qkb  = h    + NTOK*DIM;                       // [8192][512] f32
  float* kcb  = qkb  + NTOK*QKS;                       // [4][8][512][32] f32
  ushort* vctb = (ushort*)(kcb + (size_t)BATCH*NH*NB*DH);  // [4][8][32][512] bf16 (transposed)
  float* wqk  = (float*)(vctb + (size_t)BATCH*NH*NB*DH);   // [4][256][512] f32
  ushort* hb   = (ushort*)(wqk + (size_t)4*DIM*QKS);   // [8192][256] bf16
  ushort* vgu  = hb   + NTOK*DIM;                      // [8192][320] bf16
  ushort* obu  = vgu  + NTOK*VGS;                      // [8192][256] bf16
  ushort* midu = obu  + NTOK*DIM;                      // [8192][512] bf16
  ushort* wvgT = midu + NTOK*512;                      // [4][320][256] bf16
  ushort* woT  = wvgT + (size_t)4*VGS*DIM;             // [4][256][256] bf16
  ushort* w1T  = woT  + (size_t)4*DIM*DIM;             // [2][512][256] bf16
  ushort* w2T  = w1T  + (size_t)2*512*DIM;             // [2][256][512] bf16

  copy_f32<<<2048, 256, 0, stream>>>(x_in, xout, (int)(NTOK*DIM/4));
  build_wqk <<<(4*256*QKS+255)/256, 256, 0, stream>>>(Wq, Wk, wqk);
  build_wvgT<<<(4*VGS*256+255)/256, 256, 0, stream>>>(Wv, Wg, wvgT);
  build_wT  <<<(4*256*256+255)/256, 256, 0, stream>>>(Wo, woT, 4, 256, 256);
  build_wT  <<<(2*256*512+255)/256, 256, 0, stream>>>(W1, w1T, 2, 256, 512);
  build_wT  <<<(2*512*256+255)/256, 256, 0, stream>>>(W2, w2T, 2, 512, 256);

  dim3 gqk(64,8), gvg(64,5), g4(64,4), g8(64,8);
  for (int i=0;i<4;i++){
    ln_k<<<2048,256,0,stream>>>(xout, ln_a_g + i*DIM, ln_a_b + i*DIM, h, hb);
    gemm_f32<false,false,false><<<gqk,256,0,stream>>>(h, wqk + (size_t)i*DIM*QKS, nullptr, qkb, 8192,QKS,256);
    gemm_bf16<false,false,false,true><<<gvg,256,0,stream>>>(hb, wvgT + (size_t)i*VGS*DIM, nullptr, vgu, 8192,VGS,256);
    pool_k<<<2048,256,0,stream>>>(qkb, vgu, kcb, vctb);
    nsa_attn<<<1024,512,0,stream>>>(qkb, vgu, kcb, vctb, obu);
    gemm_bf16<false,false,true,false><<<g4,256,0,stream>>>(obu, woT + (size_t)i*DIM*DIM, nullptr, xout, 8192,DIM,256);
    if (i & 1){
      int l = i >> 1;
      ln_k<<<2048,256,0,stream>>>(xout, ln_f_g + l*DIM, ln_f_b + l*DIM, h, hb);
      gemm_bf16<true,true,false,true><<<g8,256,0,stream>>>(hb,   w1T + (size_t)l*512*DIM, b1 + l*512, midu, 8192,512,256);
      gemm_bf16<true,false,true,false><<<g4,256,0,stream>>>(midu, w2T + (size_t)l*DIM*512, b2 + l*DIM, xout, 8192,DIM,512);
    }
  }
}

// Round 17
// 597.173 us; speedup vs baseline: 1.0126x; 1.0126x over previous
//
#include <hip/hip_runtime.h>
#include <hip/hip_bf16.h>
#include <math.h>

#define NH 8
#define DH 32
#define DIM 256
#define SEQ 2048
#define BATCH 4
#define NB 512            // SEQ / C
#define QKS 512           // q|k packed f32 row stride
#define VGS 320           // v|g packed bf16 row stride: 256 v | 24 g | 40 pad
#define SCALE 0.17677669529663687f  // DH^-0.5

typedef short short8v __attribute__((ext_vector_type(8)));
typedef float float4v __attribute__((ext_vector_type(4)));

__device__ __forceinline__ float sigmoidf_(float x){ return 1.f/(1.f+__expf(-x)); }
__device__ __forceinline__ ushort f2bf(float f){
  uint b = __float_as_uint(f);
  return (ushort)((b + 0x7fffu + ((b>>16)&1u)) >> 16);   // RNE
}
__device__ __forceinline__ float bf2f(ushort u){ return __uint_as_float(((uint)u)<<16); }
__device__ __forceinline__ float bflo(uint u){ return __uint_as_float(u<<16); }
__device__ __forceinline__ float bfhi(uint u){ return __uint_as_float(u & 0xffff0000u); }
__device__ __forceinline__ uint pk2(float a, float b){ return (uint)f2bf(a) | ((uint)f2bf(b)<<16); }
__device__ __forceinline__ void bfu4_to_f32(uint4 u, float* f){
  f[0]=bflo(u.x); f[1]=bfhi(u.x);
  f[2]=bflo(u.y); f[3]=bfhi(u.y);
  f[4]=bflo(u.z); f[5]=bfhi(u.z);
  f[6]=bflo(u.w); f[7]=bfhi(u.w);
}
__device__ __forceinline__ void bfu2_to_f32(uint2 u, float* f){
  f[0]=bflo(u.x); f[1]=bfhi(u.x);
  f[2]=bflo(u.y); f[3]=bfhi(u.y);
}

// ---------------- copy (residual stream init) ----------------
__global__ void copy_f32(const float* __restrict__ in, float* __restrict__ out, int n4){
  int i = blockIdx.x*blockDim.x + threadIdx.x;
  if (i < n4) ((float4*)out)[i] = ((const float4*)in)[i];
}

// ---------------- weight packers ----------------
__global__ void build_wqk(const float* __restrict__ Wq, const float* __restrict__ Wk, float* __restrict__ out){
  int i = blockIdx.x*256 + threadIdx.x;          // 4*256*512
  if (i >= 4*256*QKS) return;
  int col = i & 511, rk = (i>>9)&255, l = i>>17;
  out[i] = (col < 256) ? Wq[((size_t)l*256+rk)*256+col] : Wk[((size_t)l*256+rk)*256+col-256];
}
__global__ void build_wvgT(const float* __restrict__ Wv, const float* __restrict__ Wg, ushort* __restrict__ out){
  int i = blockIdx.x*256 + threadIdx.x;          // 4*320*256 : out[l][n][k] = B[k][n]
  if (i >= 4*VGS*256) return;
  int k = i & 255, n = (i>>8)%VGS, l = i/(VGS*256);
  float v = 0.f;
  if      (n < 256) v = Wv[((size_t)l*256+k)*256+n];
  else if (n < 280) v = Wg[((size_t)l*256+k)*24 + (n-256)];
  out[i] = f2bf(v);
}
__global__ void build_wT(const float* __restrict__ in, ushort* __restrict__ out, int L, int K, int N){
  int i = blockIdx.x*256 + threadIdx.x;          // out[l][n][k] = in[l][k][n]
  if (i >= L*K*N) return;
  int k = i % K, n = (i/K) % N, l = i/(K*N);
  out[i] = f2bf(in[((size_t)l*K+k)*N+n]);
}

// ---------------- layernorm: one wave per row, dual f32+bf16 output ----------------
__global__ __launch_bounds__(256) void ln_k(const float* __restrict__ x, const float* __restrict__ g,
                                            const float* __restrict__ b, float* __restrict__ h,
                                            ushort* __restrict__ hb){
  int row  = blockIdx.x*4 + (threadIdx.x>>6);
  int lane = threadIdx.x & 63;
  int c = lane*4;
  const float* xr = x + (size_t)row*DIM + c;
  float4 v = *(const float4*)xr;
  float s = v.x+v.y+v.z+v.w;
  float q = v.x*v.x+v.y*v.y+v.z*v.z+v.w*v.w;
  #pragma unroll
  for (int off=32; off>0; off>>=1){ s += __shfl_xor(s, off); q += __shfl_xor(q, off); }
  float mean = s * (1.f/DIM);
  float var  = q * (1.f/DIM) - mean*mean;
  float rs = rsqrtf(var + 1e-5f);
  float4 gg = *(const float4*)(g + c);
  float4 bb = *(const float4*)(b + c);
  float4 o;
  o.x = (v.x-mean)*rs*gg.x + bb.x;
  o.y = (v.y-mean)*rs*gg.y + bb.y;
  o.z = (v.z-mean)*rs*gg.z + bb.z;
  o.w = (v.w-mean)*rs*gg.w + bb.w;
  *(float4*)(h + (size_t)row*DIM + c) = o;
  uint2 u;
  u.x = pk2(o.x, o.y);
  u.y = pk2(o.z, o.w);
  *(uint2*)&hb[(size_t)row*DIM + c] = u;
}

// ---------------- f32 GEMM (q|k path), guard-free, BK=32 ----------------
template<bool BIAS, bool LEAKY, bool ACC>
__global__ __launch_bounds__(256) void gemm_f32(const float* __restrict__ A, const float* __restrict__ B,
                                                const float* __restrict__ bias, float* __restrict__ C,
                                                int M, int N, int K){
  __shared__ float As[32][132];
  __shared__ float Bs[32][68];
  int tid = threadIdx.x;
  int m0 = blockIdx.x*128, n0 = blockIdx.y*64;
  int tx = tid & 15, ty = tid >> 4;
  int ar = tid >> 1;            // 0..127
  int ac = (tid & 1)*16;        // 0 or 16
  int bk = tid >> 3;            // 0..31
  int bn = (tid & 7)*8;         // 0..56
  const float* Ap = A + (size_t)(m0+ar)*K + ac;
  const float* Bp = B + (size_t)bk*N + n0 + bn;
  float4 apre[4], bpre[2];
  #pragma unroll
  for (int j=0;j<4;j++) apre[j] = *(const float4*)(Ap + 4*j);
  bpre[0] = *(const float4*)Bp;
  bpre[1] = *(const float4*)(Bp + 4);
  float acc[8][4];
  #pragma unroll
  for (int i=0;i<8;i++)
    #pragma unroll
    for (int j=0;j<4;j++) acc[i][j]=0.f;
  for (int k0=0; k0<K; k0+=32){
    #pragma unroll
    for (int j=0;j<4;j++){
      As[ac+4*j+0][ar]=apre[j].x; As[ac+4*j+1][ar]=apre[j].y;
      As[ac+4*j+2][ar]=apre[j].z; As[ac+4*j+3][ar]=apre[j].w;
    }
    *(float4*)&Bs[bk][bn]   = bpre[0];
    *(float4*)&Bs[bk][bn+4] = bpre[1];
    __syncthreads();
    if (k0 + 32 < K){
      #pragma unroll
      for (int j=0;j<4;j++) apre[j] = *(const float4*)(Ap + k0 + 32 + 4*j);
      bpre[0] = *(const float4*)(Bp + (size_t)(k0+32)*N);
      bpre[1] = *(const float4*)(Bp + (size_t)(k0+32)*N + 4);
    }
    #pragma unroll
    for (int kk=0;kk<32;kk++){
      float4 bv  = *(const float4*)&Bs[kk][tx*4];
      float4 av0 = *(const float4*)&As[kk][ty*8];
      float4 av1 = *(const float4*)&As[kk][ty*8+4];
      float av[8] = {av0.x,av0.y,av0.z,av0.w,av1.x,av1.y,av1.z,av1.w};
      float bw[4] = {bv.x,bv.y,bv.z,bv.w};
      #pragma unroll
      for (int i=0;i<8;i++)
        #pragma unroll
        for (int j=0;j<4;j++) acc[i][j] += av[i]*bw[j];
    }
    __syncthreads();
  }
  #pragma unroll
  for (int i=0;i<8;i++){
    int m = m0 + ty*8 + i;
    #pragma unroll
    for (int j=0;j<4;j++){
      int n = n0 + tx*4 + j;
      float val = acc[i][j];
      if (BIAS)  val += bias[n];
      if (LEAKY) val = val > 0.f ? val : 0.01f*val;
      float* cp = C + (size_t)m*N + n;
      if (ACC) val += *cp;
      *cp = val;
    }
  }
}

// ---------------- bf16 MFMA GEMM: C = act(A[M,K] @ Bt[N,K]^T + bias) ----------------
template<bool BIAS, bool LEAKY, bool ACC, bool OBF16>
__global__ __launch_bounds__(256) void gemm_bf16(const ushort* __restrict__ A, const ushort* __restrict__ Bt,
                                                 const float* __restrict__ bias, void* __restrict__ Cv,
                                                 int M, int N, int K){
  __shared__ ushort Al[128*64];
  __shared__ ushort Bl[64*64];
  int tid = threadIdx.x;
  int m0 = blockIdx.x*128, n0 = blockIdx.y*64;
  int w = tid>>6, lane = tid&63;
  int wm = w>>1, wn = w&1;
  float4v acc[4][2];
  #pragma unroll
  for (int i=0;i<4;i++)
    #pragma unroll
    for (int j=0;j<2;j++) acc[i][j] = (float4v){0.f,0.f,0.f,0.f};
  for (int k0=0; k0<K; k0+=64){
    #pragma unroll
    for (int i=0;i<4;i++){
      int id = tid + 256*i;
      int r = id>>3, c = id&7;
      *(uint4*)&Al[r*64 + ((c ^ (r&7))*8)] = *(const uint4*)&A[(size_t)(m0+r)*K + k0 + c*8];
    }
    #pragma unroll
    for (int i=0;i<2;i++){
      int id = tid + 256*i;
      int r = id>>3, c = id&7;
      *(uint4*)&Bl[r*64 + ((c ^ (r&7))*8)] = *(const uint4*)&Bt[(size_t)(n0+r)*K + k0 + c*8];
    }
    __syncthreads();
    #pragma unroll
    for (int kk=0; kk<2; ++kk){
      short8v a[4], bfr[2];
      #pragma unroll
      for (int mf=0; mf<4; mf++){
        int r = wm*64 + mf*16 + (lane&15);
        int c = (kk*4 + (lane>>4)) ^ (r&7);
        a[mf] = *(short8v*)&Al[r*64 + c*8];
      }
      #pragma unroll
      for (int nf=0; nf<2; nf++){
        int r = wn*32 + nf*16 + (lane&15);
        int c = (kk*4 + (lane>>4)) ^ (r&7);
        bfr[nf] = *(short8v*)&Bl[r*64 + c*8];
      }
      #pragma unroll
      for (int mf=0; mf<4; mf++)
        #pragma unroll
        for (int nf=0; nf<2; nf++)
          acc[mf][nf] = __builtin_amdgcn_mfma_f32_16x16x32_bf16(a[mf], bfr[nf], acc[mf][nf], 0, 0, 0);
    }
    __syncthreads();
  }
  #pragma unroll
  for (int nf=0; nf<2; nf++){
    int col = n0 + wn*32 + nf*16 + (lane&15);
    float bv = BIAS ? bias[col] : 0.f;
    #pragma unroll
    for (int mf=0; mf<4; mf++){
      #pragma unroll
      for (int r=0; r<4; r++){
        int row = m0 + wm*64 + mf*16 + (lane>>4)*4 + r;
        float vv = acc[mf][nf][r];
        if (BIAS) vv += bv;
        if (LEAKY) vv = vv > 0.f ? vv : 0.01f*vv;
        if (OBF16) ((ushort*)Cv)[(size_t)row*N + col] = f2bf(vv);
        else {
          float* C = (float*)Cv;
          if (ACC) vv += C[(size_t)row*N + col];
          C[(size_t)row*N + col] = vv;
        }
      }
    }
  }
}

// ---------------- mean-pool K/V blocks (C=4): kc [b][h][n][32] f32, vct [b][h][d][n] bf16 ----------------
__global__ void pool_k(const float* __restrict__ qk, const ushort* __restrict__ vg,
                       float* __restrict__ kc, ushort* __restrict__ vct){
  int i = blockIdx.x*256 + threadIdx.x;       // 0 .. B*H*NB*32-1
  if (i >= BATCH*NH*NB*DH) return;
  int d = i & 31, n = (i >> 5) & 511, h = (i >> 14) & 7, b = i >> 17;
  size_t kb = ((size_t)(b*SEQ + n*4))*QKS + 256 + h*DH + d;
  kc[i] = 0.25f*(qk[kb] + qk[kb+QKS] + qk[kb+2*QKS] + qk[kb+3*QKS]);
  size_t vb = ((size_t)(b*SEQ + n*4))*VGS + h*DH + d;
  float pv = 0.25f*(bf2f(vg[vb]) + bf2f(vg[vb+VGS]) + bf2f(vg[vb+2*VGS]) + bf2f(vg[vb+3*VGS]));
  vct[(((size_t)(b*NH + h))*DH + d)*NB + n] = f2bf(pv);   // transposed: MFMA-A-ready
}

// ---------------- fused NSA attention v11c: 8-wave phase 1, reg-direct phase 2 ----------------
// Identical to v11b except __launch_bounds__(512,4): the (512,6) bound capped VGPRs
// at ~85 and the allocator spilled the qv[32]+ps+acc state to scratch (R16: VGPR=40,
// WRITE_SIZE 4->30MB = scratch traffic). (512,4) -> 128-VGPR budget, 2 blocks/CU,
// no spill.
__global__ __launch_bounds__(512, 4) void nsa_attn(
    const float* __restrict__ qk, const ushort* __restrict__ vg,
    const float* __restrict__ kc, const ushort* __restrict__ vct,
    ushort* __restrict__ o)
{
  __shared__ float  kt[64*32];       // 8 KB f32 kc tile
  __shared__ ushort vcT[32*72];      // 4.5 KB bf16 Vc^T tile [d][n], pad 8
  __shared__ ushort Pl[64*72];       // 9 KB bf16 P tile [tok][n], pad 8
  __shared__ float4 meta[8*64];      // 8 KB (l, best, bestn, -)   -> 29.5 KB
  int e = blockIdx.x;
  int hh = e & 7;
  int b  = (e >> 3) & 3;
  int qq = (e >> 5) & 7;
  int r  = e >> 8;
  int g  = (r==0) ? (31-qq) : (r==1) ? qq : (r==2) ? (23-qq) : (8+qq);
  int tid = threadIdx.x;
  int w = tid >> 6, lane = tid & 63;
  const float*  kcg  = kc  + ((size_t)(b*NH + hh)*NB)*DH;
  const ushort* vctg = vct + ((size_t)(b*NH + hh)*DH)*NB;

  float4v acc0 = (float4v){0.f,0.f,0.f,0.f};
  float4v acc1 = (float4v){0.f,0.f,0.f,0.f};

  // ---- phase 1
  {
    int t = g*64 + lane;
    int own = t >> 2, nvis = (t+1) >> 2;
    int nmax = 16*(g+1);                  // block-uniform visibility bound
    float qv[32];
    {
      const float4* qr = (const float4*)(qk + ((size_t)b*SEQ + t)*QKS + hh*DH);
      #pragma unroll
      for (int d8=0; d8<8; d8++){
        float4 a4 = qr[d8];
        qv[4*d8]=a4.x; qv[4*d8+1]=a4.y; qv[4*d8+2]=a4.z; qv[4*d8+3]=a4.w;
      }
    }
    float l = 0.f, best = -1e30f;
    int bn1 = -1;

    int tiles = (g + 4) >> 2;             // ceil(16(g+1)/64)
    for (int ti=0; ti<tiles; ++ti){
      int base = ti*64;
      if (ti) __syncthreads();            // prev tile fully consumed
      {                                   // stage: kt 512xfloat4 (all threads), vcT 256xuint4
        const float4* sk = (const float4*)(kcg + (size_t)base*DH);
        ((float4*)kt)[tid] = sk[tid];
        if (tid < 256){
          int sd = tid >> 3, sn = (tid & 7)*8;
          *(uint4*)&vcT[sd*72 + sn] = *(const uint4*)&vctg[(size_t)sd*NB + base + sn];
        }
      }
      __syncthreads();
      // score phase: wave w owns CONTIGUOUS rows [8w, 8w+8) -> Pl k-index == n_local
      int jm = nmax - base - 8*w;         // uniform early exit past nvis_max
      jm = jm < 0 ? 0 : (jm > 8 ? 8 : jm);
      float ps[8];
      #pragma unroll
      for (int j=0;j<8;j++) ps[j]=0.f;
      for (int j=0; j<jm; ++j){
        int rr = 8*w + j;
        int n = base + rr;
        const float4* kp = (const float4*)&kt[rr*32];
        float s = 0.f;
        #pragma unroll
        for (int d8=0; d8<8; d8++){       // exact grouped-4 ordering: argmax-stable
          float4 k4 = kp[d8];
          s += qv[4*d8]*k4.x + qv[4*d8+1]*k4.y + qv[4*d8+2]*k4.z + qv[4*d8+3]*k4.w;
        }
        s *= SCALE;
        bool act = (n < nvis);
        if (act && n != own && s > best){ best = s; bn1 = n; }  // ascending n in-wave
        float p = act ? __expf(s) : 0.f;  // max-free: |s| small, exp safe
        l += p;
        ps[j] = p;
      }
      {                                   // P[lane][8w .. 8w+8) as 1x b128 (identity k-map)
        uint4 u0;
        u0.x = pk2(ps[0],ps[1]);  u0.y = pk2(ps[2],ps[3]);
        u0.z = pk2(ps[4],ps[5]);  u0.w = pk2(ps[6],ps[7]);
        *(uint4*)&Pl[lane*72 + w*8] = u0;
      }
      __syncthreads();                    // P complete
      // MFMA (waves 0-3): A=vcT rows d, B=Pl rows [16w,16w+16), K=64 via 2 ksteps
      if (w < 4){
        #pragma unroll
        for (int ks=0; ks<2; ++ks){
          short8v bfrag = *(short8v*)&Pl [(16*w + (lane&15))*72 + ks*32 + (lane>>4)*8];
          short8v a0    = *(short8v*)&vcT[(lane&15)*72          + ks*32 + (lane>>4)*8];
          short8v a1    = *(short8v*)&vcT[((lane&15)+16)*72     + ks*32 + (lane>>4)*8];
          acc0 = __builtin_amdgcn_mfma_f32_16x16x32_bf16(a0, bfrag, acc0, 0, 0, 0);
          acc1 = __builtin_amdgcn_mfma_f32_16x16x32_bf16(a1, bfrag, acc1, 0, 0, 0);
        }
      }
    }
    meta[w*64 + lane] = make_float4(l, best, __int_as_float(bn1), 0.f);
  }
  __syncthreads();

  // ---- phase 2 (waves 0-3): token = g*64 + w*16 + (lane&15); lane m=lane>>4 owns
  //      d-set {4m..4m+3} u {16+4m..16+4m+3}; oc comes straight from acc0/acc1.
  if (w < 4){
    int c = lane & 15, m = lane >> 4;
    int tokidx = w*16 + c;
    int t = g*64 + tokidx;
    int own = t >> 2, nvis = (t+1) >> 2;
    int dA = 4*m, dB = 16 + 4*m;
    float q8[8];
    {
      const float* qrow = qk + ((size_t)b*SEQ + t)*QKS + hh*DH;
      float4 a4 = *(const float4*)(qrow + dA);
      float4 b4 = *(const float4*)(qrow + dB);
      q8[0]=a4.x; q8[1]=a4.y; q8[2]=a4.z; q8[3]=a4.w;
      q8[4]=b4.x; q8[5]=b4.y; q8[6]=b4.z; q8[7]=b4.w;
    }
    float out8[8];
    #pragma unroll
    for (int j=0;j<4;j++){ out8[j] = acc0[j]; out8[4+j] = acc1[j]; }
    float ll = 0.f, bb = -1e30f;
    int bn = (own==0) ? 1 : 0;         // jax top_k fallback
    #pragma unroll
    for (int sp=0; sp<8; ++sp){
      float4 m4 = meta[sp*64 + tokidx];
      ll += m4.x;
      int mi = __float_as_int(m4.z);
      // interleaved splits: equal scores resolve to the lower n (mi>=0 excludes empties)
      if (m4.y > bb || (m4.y == bb && mi >= 0 && mi < bn)){ bb = m4.y; bn = mi; }
    }
    const ushort* gr = vg + ((size_t)b*SEQ + t)*VGS + 256;
    float g0 = sigmoidf_(bf2f(gr[hh])), g1 = sigmoidf_(bf2f(gr[8+hh])), g2 = sigmoidf_(bf2f(gr[16+hh]));
    float inv = (nvis > 0) ? g0/ll : 0.f;
    #pragma unroll
    for (int j=0;j<8;j++) out8[j] *= inv;

    // selection branch: own block + best block, causal token mask, d-split dots
    const float*  kb2 = qk + (size_t)b*SEQ*QKS + 256 + hh*DH;
    const ushort* vb2 = vg + (size_t)b*SEQ*VGS + hh*DH;
    float s2[8];
    float m2 = -1e30f;
    #pragma unroll
    for (int ki=0; ki<8; ++ki){
      int tt = (ki<4 ? own : bn)*4 + (ki&3);
      float s = -1e30f;
      if (tt <= t){                       // uniform across the 4 lanes of this token
        const float* kr = kb2 + (size_t)tt*QKS;
        float4 a4 = *(const float4*)(kr + dA);
        float4 c4 = *(const float4*)(kr + dB);
        float ps = q8[0]*a4.x + q8[1]*a4.y + q8[2]*a4.z + q8[3]*a4.w
                 + q8[4]*c4.x + q8[5]*c4.y + q8[6]*c4.z + q8[7]*c4.w;
        ps += __shfl_xor(ps, 16);
        ps += __shfl_xor(ps, 32);
        s = ps*SCALE;
        m2 = fmaxf(m2, s);
      }
      s2[ki] = s;
    }
    float l2 = 0.f;
    #pragma unroll
    for (int ki=0; ki<8; ++ki)
      if (s2[ki] > -1e29f) l2 += __expf(s2[ki] - m2);
    float inv2 = g1/l2;                   // l2 >= 1 (self token always visible)
    #pragma unroll
    for (int ki=0; ki<8; ++ki){
      int tt = (ki<4 ? own : bn)*4 + (ki&3);
      if (tt <= t){
        float pw = __expf(s2[ki] - m2) * inv2;
        float fA[4], fB[4];
        bfu2_to_f32(*(const uint2*)(vb2 + (size_t)tt*VGS + dA), fA);
        bfu2_to_f32(*(const uint2*)(vb2 + (size_t)tt*VGS + dB), fB);
        #pragma unroll
        for (int j=0;j<4;j++){ out8[j] += pw*fA[j]; out8[4+j] += pw*fB[j]; }
      }
    }

    // sliding window (W=2): tokens t-1, t
    int tp = (t>0) ? t-1 : 0;
    float sa, sb;
    {
      const float* ka = kb2 + (size_t)tp*QKS;
      const float* kb4= kb2 + (size_t)t *QKS;
      float4 a0 = *(const float4*)(ka + dA), a1 = *(const float4*)(ka + dB);
      float4 b0 = *(const float4*)(kb4 + dA), b1 = *(const float4*)(kb4 + dB);
      float pa_ = q8[0]*a0.x + q8[1]*a0.y + q8[2]*a0.z + q8[3]*a0.w
                + q8[4]*a1.x + q8[5]*a1.y + q8[6]*a1.z + q8[7]*a1.w;
      float pb_ = q8[0]*b0.x + q8[1]*b0.y + q8[2]*b0.z + q8[3]*b0.w
                + q8[4]*b1.x + q8[5]*b1.y + q8[6]*b1.z + q8[7]*b1.w;
      pa_ += __shfl_xor(pa_, 16); pa_ += __shfl_xor(pa_, 32);
      pb_ += __shfl_xor(pb_, 16); pb_ += __shfl_xor(pb_, 32);
      sa = pa_*SCALE; sb = pb_*SCALE;
    }
    float m3 = (t>0) ? fmaxf(sa, sb) : sb;
    float pa = (t>0) ? __expf(sa-m3) : 0.f;
    float pb = __expf(sb-m3);
    float inv3 = g2/(pa+pb);
    float va[4], vaB[4], vbv[4], vbB[4];
    bfu2_to_f32(*(const uint2*)(vb2 + (size_t)tp*VGS + dA), va);
    bfu2_to_f32(*(const uint2*)(vb2 + (size_t)tp*VGS + dB), vaB);
    bfu2_to_f32(*(const uint2*)(vb2 + (size_t)t *VGS + dA), vbv);
    bfu2_to_f32(*(const uint2*)(vb2 + (size_t)t *VGS + dB), vbB);
    ushort* orow = o + ((size_t)b*SEQ + t)*DIM + hh*DH;
    float rrA[4], rrB[4];
    #pragma unroll
    for (int j=0;j<4;j++){
      rrA[j] = out8[j]   + (pa*va[j]  + pb*vbv[j])*inv3;
      rrB[j] = out8[4+j] + (pa*vaB[j] + pb*vbB[j])*inv3;
    }
    uint2 uA, uB;
    uA.x = pk2(rrA[0], rrA[1]); uA.y = pk2(rrA[2], rrA[3]);
    uB.x = pk2(rrB[0], rrB[1]); uB.y = pk2(rrB[2], rrB[3]);
    *(uint2*)&orow[dA] = uA;
    *(uint2*)&orow[dB] = uB;
  }
}

extern "C" void kernel_launch(void* const* d_in, const int* in_sizes, int n_in,
                              void* d_out, int out_size, void* d_ws, size_t ws_size,
                              hipStream_t stream) {
  const float* x_in   = (const float*)d_in[0];
  const float* ln_a_g = (const float*)d_in[1];
  const float* ln_a_b = (const float*)d_in[2];
  const float* Wq     = (const float*)d_in[3];
  const float* Wk     = (const float*)d_in[4];
  const float* Wv     = (const float*)d_in[5];
  const float* Wg     = (const float*)d_in[6];
  const float* Wo     = (const float*)d_in[7];
  const float* ln_f_g = (const float*)d_in[8];
  const float* ln_f_b = (const float*)d_in[9];
  const float* W1     = (const float*)d_in[10];
  const float* b1     = (const float*)d_in[11];
  const float* W2     = (const float*)d_in[12];
  const float* b2     = (const float*)d_in[13];

  float* xout = (float*)d_out;             // running residual stream [8192][256] f32
  float* ws = (float*)d_ws;
  const size_t NTOK = (size_t)BATCH*SEQ;   // 8192
  float* h    = ws;                                    // [8192][256] f32
  float* qkb  = h    + NTOK*DIM;                       // [8192][512] f32
  float* kcb  = qkb  + NTOK*QKS;                       // [4][8][512][32] f32
  ushort* vctb = (ushort*)(kcb + (size_t)BATCH*NH*NB*DH);  // [4][8][32][512] bf16 (transposed)
  float* wqk  = (float*)(vctb + (size_t)BATCH*NH*NB*DH);   // [4][256][512] f32
  ushort* hb   = (ushort*)(wqk + (size_t)4*DIM*QKS);   // [8192][256] bf16
  ushort* vgu  = hb   + NTOK*DIM;                      // [8192][320] bf16
  ushort* obu  = vgu  + NTOK*VGS;                      // [8192][256] bf16
  ushort* midu = obu  + NTOK*DIM;                      // [8192][512] bf16
  ushort* wvgT = midu + NTOK*512;                      // [4][320][256] bf16
  ushort* woT  = wvgT + (size_t)4*VGS*DIM;             // [4][256][256] bf16
  ushort* w1T  = woT  + (size_t)4*DIM*DIM;             // [2][512][256] bf16
  ushort* w2T  = w1T  + (size_t)2*512*DIM;             // [2][256][512] bf16

  copy_f32<<<2048, 256, 0, stream>>>(x_in, xout, (int)(NTOK*DIM/4));
  build_wqk <<<(4*256*QKS+255)/256, 256, 0, stream>>>(Wq, Wk, wqk);
  build_wvgT<<<(4*VGS*256+255)/256, 256, 0, stream>>>(Wv, Wg, wvgT);
  build_wT  <<<(4*256*256+255)/256, 256, 0, stream>>>(Wo, woT, 4, 256, 256);
  build_wT  <<<(2*256*512+255)/256, 256, 0, stream>>>(W1, w1T, 2, 256, 512);
  build_wT  <<<(2*512*256+255)/256, 256, 0, stream>>>(W2, w2T, 2, 512, 256);

  dim3 gqk(64,8), gvg(64,5), g4(64,4), g8(64,8);
  for (int i=0;i<4;i++){
    ln_k<<<2048,256,0,stream>>>(xout, ln_a_g + i*DIM, ln_a_b + i*DIM, h, hb);
    gemm_f32<false,false,false><<<gqk,256,0,stream>>>(h, wqk + (size_t)i*DIM*QKS, nullptr, qkb, 8192,QKS,256);
    gemm_bf16<false,false,false,true><<<gvg,256,0,stream>>>(hb, wvgT + (size_t)i*VGS*DIM, nullptr, vgu, 8192,VGS,256);
    pool_k<<<2048,256,0,stream>>>(qkb, vgu, kcb, vctb);
    nsa_attn<<<1024,512,0,stream>>>(qkb, vgu, kcb, vctb, obu);
    gemm_bf16<false,false,true,false><<<g4,256,0,stream>>>(obu, woT + (size_t)i*DIM*DIM, nullptr, xout, 8192,DIM,256);
    if (i & 1){
      int l = i >> 1;
      ln_k<<<2048,256,0,stream>>>(xout, ln_f_g + l*DIM, ln_f_b + l*DIM, h, hb);
      gemm_bf16<true,true,false,true><<<g8,256,0,stream>>>(hb,   w1T + (size_t)l*512*DIM, b1 + l*512, midu, 8192,512,256);
      gemm_bf16<true,false,true,false><<<g4,256,0,stream>>>(midu, w2T + (size_t)l*DIM*512, b2 + l*DIM, xout, 8192,DIM,512);
    }
  }
}

// Round 18
// 591.683 us; speedup vs baseline: 1.0220x; 1.0093x over previous
//
#include <hip/hip_runtime.h>
#include <hip/hip_bf16.h>
#include <math.h>

#define NH 8
#define DH 32
#define DIM 256
#define SEQ 2048
#define BATCH 4
#define NB 512            // SEQ / C
#define QKS 512           // q|k packed f32 row stride
#define VGS 320           // v|g packed bf16 row stride: 256 v | 24 g | 40 pad
#define SCALE 0.17677669529663687f  // DH^-0.5

typedef short short8v __attribute__((ext_vector_type(8)));
typedef float float4v __attribute__((ext_vector_type(4)));

__device__ __forceinline__ float sigmoidf_(float x){ return 1.f/(1.f+__expf(-x)); }
__device__ __forceinline__ ushort f2bf(float f){
  uint b = __float_as_uint(f);
  return (ushort)((b + 0x7fffu + ((b>>16)&1u)) >> 16);   // RNE
}
__device__ __forceinline__ float bf2f(ushort u){ return __uint_as_float(((uint)u)<<16); }
__device__ __forceinline__ float bflo(uint u){ return __uint_as_float(u<<16); }
__device__ __forceinline__ float bfhi(uint u){ return __uint_as_float(u & 0xffff0000u); }
__device__ __forceinline__ uint pk2(float a, float b){ return (uint)f2bf(a) | ((uint)f2bf(b)<<16); }
__device__ __forceinline__ void bfu2_to_f32(uint2 u, float* f){
  f[0]=bflo(u.x); f[1]=bfhi(u.x);
  f[2]=bflo(u.y); f[3]=bfhi(u.y);
}

// ---------------- copy (residual stream init) ----------------
__global__ void copy_f32(const float* __restrict__ in, float* __restrict__ out, int n4){
  int i = blockIdx.x*blockDim.x + threadIdx.x;
  if (i < n4) ((float4*)out)[i] = ((const float4*)in)[i];
}

// ---------------- weight packers ----------------
__global__ void build_wqk(const float* __restrict__ Wq, const float* __restrict__ Wk, float* __restrict__ out){
  int i = blockIdx.x*256 + threadIdx.x;          // 4*256*512
  if (i >= 4*256*QKS) return;
  int col = i & 511, rk = (i>>9)&255, l = i>>17;
  out[i] = (col < 256) ? Wq[((size_t)l*256+rk)*256+col] : Wk[((size_t)l*256+rk)*256+col-256];
}
__global__ void build_wvgT(const float* __restrict__ Wv, const float* __restrict__ Wg, ushort* __restrict__ out){
  int i = blockIdx.x*256 + threadIdx.x;          // 4*320*256 : out[l][n][k] = B[k][n]
  if (i >= 4*VGS*256) return;
  int k = i & 255, n = (i>>8)%VGS, l = i/(VGS*256);
  float v = 0.f;
  if      (n < 256) v = Wv[((size_t)l*256+k)*256+n];
  else if (n < 280) v = Wg[((size_t)l*256+k)*24 + (n-256)];
  out[i] = f2bf(v);
}
__global__ void build_wT(const float* __restrict__ in, ushort* __restrict__ out, int L, int K, int N){
  int i = blockIdx.x*256 + threadIdx.x;          // out[l][n][k] = in[l][k][n]
  if (i >= L*K*N) return;
  int k = i % K, n = (i/K) % N, l = i/(K*N);
  out[i] = f2bf(in[((size_t)l*K+k)*N+n]);
}

// ---------------- layernorm: one wave per row, dual f32+bf16 output ----------------
__global__ __launch_bounds__(256) void ln_k(const float* __restrict__ x, const float* __restrict__ g,
                                            const float* __restrict__ b, float* __restrict__ h,
                                            ushort* __restrict__ hb){
  int row  = blockIdx.x*4 + (threadIdx.x>>6);
  int lane = threadIdx.x & 63;
  int c = lane*4;
  const float* xr = x + (size_t)row*DIM + c;
  float4 v = *(const float4*)xr;
  float s = v.x+v.y+v.z+v.w;
  float q = v.x*v.x+v.y*v.y+v.z*v.z+v.w*v.w;
  #pragma unroll
  for (int off=32; off>0; off>>=1){ s += __shfl_xor(s, off); q += __shfl_xor(q, off); }
  float mean = s * (1.f/DIM);
  float var  = q * (1.f/DIM) - mean*mean;
  float rs = rsqrtf(var + 1e-5f);
  float4 gg = *(const float4*)(g + c);
  float4 bb = *(const float4*)(b + c);
  float4 o;
  o.x = (v.x-mean)*rs*gg.x + bb.x;
  o.y = (v.y-mean)*rs*gg.y + bb.y;
  o.z = (v.z-mean)*rs*gg.z + bb.z;
  o.w = (v.w-mean)*rs*gg.w + bb.w;
  *(float4*)(h + (size_t)row*DIM + c) = o;
  uint2 u;
  u.x = pk2(o.x, o.y);
  u.y = pk2(o.z, o.w);
  *(uint2*)&hb[(size_t)row*DIM + c] = u;
}

// ---------------- f32 GEMM (q|k path), guard-free, BK=32 ----------------
template<bool BIAS, bool LEAKY, bool ACC>
__global__ __launch_bounds__(256) void gemm_f32(const float* __restrict__ A, const float* __restrict__ B,
                                                const float* __restrict__ bias, float* __restrict__ C,
                                                int M, int N, int K){
  __shared__ float As[32][132];
  __shared__ float Bs[32][68];
  int tid = threadIdx.x;
  int m0 = blockIdx.x*128, n0 = blockIdx.y*64;
  int tx = tid & 15, ty = tid >> 4;
  int ar = tid >> 1;            // 0..127
  int ac = (tid & 1)*16;        // 0 or 16
  int bk = tid >> 3;            // 0..31
  int bn = (tid & 7)*8;         // 0..56
  const float* Ap = A + (size_t)(m0+ar)*K + ac;
  const float* Bp = B + (size_t)bk*N + n0 + bn;
  float4 apre[4], bpre[2];
  #pragma unroll
  for (int j=0;j<4;j++) apre[j] = *(const float4*)(Ap + 4*j);
  bpre[0] = *(const float4*)Bp;
  bpre[1] = *(const float4*)(Bp + 4);
  float acc[8][4];
  #pragma unroll
  for (int i=0;i<8;i++)
    #pragma unroll
    for (int j=0;j<4;j++) acc[i][j]=0.f;
  for (int k0=0; k0<K; k0+=32){
    #pragma unroll
    for (int j=0;j<4;j++){
      As[ac+4*j+0][ar]=apre[j].x; As[ac+4*j+1][ar]=apre[j].y;
      As[ac+4*j+2][ar]=apre[j].z; As[ac+4*j+3][ar]=apre[j].w;
    }
    *(float4*)&Bs[bk][bn]   = bpre[0];
    *(float4*)&Bs[bk][bn+4] = bpre[1];
    __syncthreads();
    if (k0 + 32 < K){
      #pragma unroll
      for (int j=0;j<4;j++) apre[j] = *(const float4*)(Ap + k0 + 32 + 4*j);
      bpre[0] = *(const float4*)(Bp + (size_t)(k0+32)*N);
      bpre[1] = *(const float4*)(Bp + (size_t)(k0+32)*N + 4);
    }
    #pragma unroll
    for (int kk=0;kk<32;kk++){
      float4 bv  = *(const float4*)&Bs[kk][tx*4];
      float4 av0 = *(const float4*)&As[kk][ty*8];
      float4 av1 = *(const float4*)&As[kk][ty*8+4];
      float av[8] = {av0.x,av0.y,av0.z,av0.w,av1.x,av1.y,av1.z,av1.w};
      float bw[4] = {bv.x,bv.y,bv.z,bv.w};
      #pragma unroll
      for (int i=0;i<8;i++)
        #pragma unroll
        for (int j=0;j<4;j++) acc[i][j] += av[i]*bw[j];
    }
    __syncthreads();
  }
  #pragma unroll
  for (int i=0;i<8;i++){
    int m = m0 + ty*8 + i;
    #pragma unroll
    for (int j=0;j<4;j++){
      int n = n0 + tx*4 + j;
      float val = acc[i][j];
      if (BIAS)  val += bias[n];
      if (LEAKY) val = val > 0.f ? val : 0.01f*val;
      float* cp = C + (size_t)m*N + n;
      if (ACC) val += *cp;
      *cp = val;
    }
  }
}

// ---------------- bf16 MFMA GEMM: C = act(A[M,K] @ Bt[N,K]^T + bias) ----------------
template<bool BIAS, bool LEAKY, bool ACC, bool OBF16>
__global__ __launch_bounds__(256) void gemm_bf16(const ushort* __restrict__ A, const ushort* __restrict__ Bt,
                                                 const float* __restrict__ bias, void* __restrict__ Cv,
                                                 int M, int N, int K){
  __shared__ ushort Al[128*64];
  __shared__ ushort Bl[64*64];
  int tid = threadIdx.x;
  int m0 = blockIdx.x*128, n0 = blockIdx.y*64;
  int w = tid>>6, lane = tid&63;
  int wm = w>>1, wn = w&1;
  float4v acc[4][2];
  #pragma unroll
  for (int i=0;i<4;i++)
    #pragma unroll
    for (int j=0;j<2;j++) acc[i][j] = (float4v){0.f,0.f,0.f,0.f};
  for (int k0=0; k0<K; k0+=64){
    #pragma unroll
    for (int i=0;i<4;i++){
      int id = tid + 256*i;
      int r = id>>3, c = id&7;
      *(uint4*)&Al[r*64 + ((c ^ (r&7))*8)] = *(const uint4*)&A[(size_t)(m0+r)*K + k0 + c*8];
    }
    #pragma unroll
    for (int i=0;i<2;i++){
      int id = tid + 256*i;
      int r = id>>3, c = id&7;
      *(uint4*)&Bl[r*64 + ((c ^ (r&7))*8)] = *(const uint4*)&Bt[(size_t)(n0+r)*K + k0 + c*8];
    }
    __syncthreads();
    #pragma unroll
    for (int kk=0; kk<2; ++kk){
      short8v a[4], bfr[2];
      #pragma unroll
      for (int mf=0; mf<4; mf++){
        int r = wm*64 + mf*16 + (lane&15);
        int c = (kk*4 + (lane>>4)) ^ (r&7);
        a[mf] = *(short8v*)&Al[r*64 + c*8];
      }
      #pragma unroll
      for (int nf=0; nf<2; nf++){
        int r = wn*32 + nf*16 + (lane&15);
        int c = (kk*4 + (lane>>4)) ^ (r&7);
        bfr[nf] = *(short8v*)&Bl[r*64 + c*8];
      }
      #pragma unroll
      for (int mf=0; mf<4; mf++)
        #pragma unroll
        for (int nf=0; nf<2; nf++)
          acc[mf][nf] = __builtin_amdgcn_mfma_f32_16x16x32_bf16(a[mf], bfr[nf], acc[mf][nf], 0, 0, 0);
    }
    __syncthreads();
  }
  #pragma unroll
  for (int nf=0; nf<2; nf++){
    int col = n0 + wn*32 + nf*16 + (lane&15);
    float bv = BIAS ? bias[col] : 0.f;
    #pragma unroll
    for (int mf=0; mf<4; mf++){
      #pragma unroll
      for (int r=0; r<4; r++){
        int row = m0 + wm*64 + mf*16 + (lane>>4)*4 + r;
        float vv = acc[mf][nf][r];
        if (BIAS) vv += bv;
        if (LEAKY) vv = vv > 0.f ? vv : 0.01f*vv;
        if (OBF16) ((ushort*)Cv)[(size_t)row*N + col] = f2bf(vv);
        else {
          float* C = (float*)Cv;
          if (ACC) vv += C[(size_t)row*N + col];
          C[(size_t)row*N + col] = vv;
        }
      }
    }
  }
}

// ---------------- mean-pool K/V blocks (C=4): kc [b][h][n][32] f32, vct [b][h][d][n] bf16 ----------------
__global__ void pool_k(const float* __restrict__ qk, const ushort* __restrict__ vg,
                       float* __restrict__ kc, ushort* __restrict__ vct){
  int i = blockIdx.x*256 + threadIdx.x;       // 0 .. B*H*NB*32-1
  if (i >= BATCH*NH*NB*DH) return;
  int d = i & 31, n = (i >> 5) & 511, h = (i >> 14) & 7, b = i >> 17;
  size_t kb = ((size_t)(b*SEQ + n*4))*QKS + 256 + h*DH + d;
  kc[i] = 0.25f*(qk[kb] + qk[kb+QKS] + qk[kb+2*QKS] + qk[kb+3*QKS]);
  size_t vb = ((size_t)(b*SEQ + n*4))*VGS + h*DH + d;
  float pv = 0.25f*(bf2f(vg[vb]) + bf2f(vg[vb+VGS]) + bf2f(vg[vb+2*VGS]) + bf2f(vg[vb+3*VGS]));
  vct[(((size_t)(b*NH + h))*DH + d)*NB + n] = f2bf(pv);   // transposed: MFMA-A-ready
}

// ---------------- fused NSA attention v12: 128 tokens/block, 2 tok/lane ----------------
// 16 groups x 128 tokens per (b,h). Grid 512 x 256 threads (4 waves).
// Block e: hh=e&7 (XCD slot), b=(e>>3)&3, gc=(e>>5)&7; g = e<256 ? 15-gc : gc
//   (heavy half dispatched first; blocks e and e+256 pair to constant weight).
// Rationale: phase 1 is LDS-return-bus bound (broadcast k-rows). Serving 128
//   tokens per row-visit halves total row-visits (8448 -> 4352 rows/bh) -> LDS
//   floor ~22us. Structure is EXACTLY R14's proven one, doubled: lane owns
//   t0=g*128+lane and t1=t0+64; wave w scores contiguous rows [16w,16w+16)
//   (identity Pl k-map on both MFMA operands); MFMA adds a second B-fragment
//   (Pl rows 64+16w..) -> acc2/3; phase 2 runs twice per lane.
// Scores keep the exact grouped-4 f32 dot -> argmax preserved; cross-split
//   combine keeps the equal-score -> lower-n guard (tile-interleaved splits).
__global__ __launch_bounds__(256, 2) void nsa_attn(
    const float* __restrict__ qk, const ushort* __restrict__ vg,
    const float* __restrict__ kc, const ushort* __restrict__ vct,
    ushort* __restrict__ o)
{
  __shared__ float  kt[64*32];       // 8 KB f32 kc tile
  __shared__ ushort vcT[32*72];      // 4.5 KB bf16 Vc^T tile [d][n], pad 8
  __shared__ ushort Pl[128*72];      // 18 KB bf16 P tile [tok][n], pad 8
  __shared__ float4 meta[4*128];     // 8 KB (l, best, bestn, -)   -> 38.5 KB
  int e = blockIdx.x;
  int hh = e & 7;
  int b  = (e >> 3) & 3;
  int gc = (e >> 5) & 7;
  int g  = (e < 256) ? (15 - gc) : gc;
  int tid = threadIdx.x;
  int w = tid >> 6, lane = tid & 63;
  const float*  kcg  = kc  + ((size_t)(b*NH + hh)*NB)*DH;
  const ushort* vctg = vct + ((size_t)(b*NH + hh)*DH)*NB;

  float4v acc0 = (float4v){0.f,0.f,0.f,0.f};
  float4v acc1 = (float4v){0.f,0.f,0.f,0.f};
  float4v acc2 = (float4v){0.f,0.f,0.f,0.f};
  float4v acc3 = (float4v){0.f,0.f,0.f,0.f};

  // ---- phase 1
  {
    int t0 = g*128 + lane, t1 = t0 + 64;
    int own0 = t0 >> 2, nvis0 = (t0+1) >> 2;
    int own1 = t1 >> 2, nvis1 = (t1+1) >> 2;
    int nmax = 32*(g+1);                  // block-uniform visibility bound
    float qv0[32], qv1[32];
    {
      const float4* q0 = (const float4*)(qk + ((size_t)b*SEQ + t0)*QKS + hh*DH);
      const float4* q1 = (const float4*)(qk + ((size_t)b*SEQ + t1)*QKS + hh*DH);
      #pragma unroll
      for (int d8=0; d8<8; d8++){
        float4 a4 = q0[d8]; float4 b4 = q1[d8];
        qv0[4*d8]=a4.x; qv0[4*d8+1]=a4.y; qv0[4*d8+2]=a4.z; qv0[4*d8+3]=a4.w;
        qv1[4*d8]=b4.x; qv1[4*d8+1]=b4.y; qv1[4*d8+2]=b4.z; qv1[4*d8+3]=b4.w;
      }
    }
    float l0 = 0.f, l1 = 0.f, best0 = -1e30f, best1 = -1e30f;
    int ibn0 = -1, ibn1 = -1;

    int tiles = (g + 2) >> 1;             // ceil(32(g+1)/64)
    for (int ti=0; ti<tiles; ++ti){
      int base = ti*64;
      if (ti) __syncthreads();            // prev tile fully consumed
      {                                   // stage: kt 2 float4/thr, vcT 1 uint4/thr
        const float4* sk = (const float4*)(kcg + (size_t)base*DH);
        ((float4*)kt)[tid]     = sk[tid];
        ((float4*)kt)[tid+256] = sk[tid+256];
        int sd = tid >> 3, sn = (tid & 7)*8;
        *(uint4*)&vcT[sd*72 + sn] = *(const uint4*)&vctg[(size_t)sd*NB + base + sn];
      }
      __syncthreads();
      // score phase: wave w owns CONTIGUOUS rows [16w, 16w+16) -> identity Pl k-map
      int jm = nmax - base - 16*w;        // uniform early exit past nvis_max
      jm = jm < 0 ? 0 : (jm > 16 ? 16 : jm);
      uint psu0[8], psu1[8];
      #pragma unroll
      for (int j=0;j<8;j++){ psu0[j]=0u; psu1[j]=0u; }
      for (int j=0; j<jm; j+=2){
        int rr0 = 16*w + j, rr1 = rr0 + 1;
        int n0 = base + rr0, n1 = base + rr1;
        bool row1ok = (j+1 < jm);
        const float4* kp0 = (const float4*)&kt[rr0*32];
        const float4* kp1 = (const float4*)&kt[rr1*32];
        float s00=0.f, s10=0.f, s01=0.f, s11=0.f;
        #pragma unroll
        for (int d8=0; d8<8; d8++){       // exact grouped-4 ordering: argmax-stable
          float4 k4a = kp0[d8];
          float4 k4b = kp1[d8];
          s00 += qv0[4*d8]*k4a.x + qv0[4*d8+1]*k4a.y + qv0[4*d8+2]*k4a.z + qv0[4*d8+3]*k4a.w;
          s10 += qv1[4*d8]*k4a.x + qv1[4*d8+1]*k4a.y + qv1[4*d8+2]*k4a.z + qv1[4*d8+3]*k4a.w;
          s01 += qv0[4*d8]*k4b.x + qv0[4*d8+1]*k4b.y + qv0[4*d8+2]*k4b.z + qv0[4*d8+3]*k4b.w;
          s11 += qv1[4*d8]*k4b.x + qv1[4*d8+1]*k4b.y + qv1[4*d8+2]*k4b.z + qv1[4*d8+3]*k4b.w;
        }
        s00 *= SCALE; s10 *= SCALE; s01 *= SCALE; s11 *= SCALE;
        // row0 before row1: ascending n, strict > = lowest-index tie-break
        bool a00 = (n0 < nvis0), a10 = (n0 < nvis1);
        if (a00 && n0 != own0 && s00 > best0){ best0 = s00; ibn0 = n0; }
        if (a10 && n0 != own1 && s10 > best1){ best1 = s10; ibn1 = n0; }
        float p00 = a00 ? __expf(s00) : 0.f;   // max-free: |s| small, exp safe
        float p10 = a10 ? __expf(s10) : 0.f;
        float p01 = 0.f, p11 = 0.f;
        if (row1ok){
          bool a01 = (n1 < nvis0), a11 = (n1 < nvis1);
          if (a01 && n1 != own0 && s01 > best0){ best0 = s01; ibn0 = n1; }
          if (a11 && n1 != own1 && s11 > best1){ best1 = s11; ibn1 = n1; }
          p01 = a01 ? __expf(s01) : 0.f;
          p11 = a11 ? __expf(s11) : 0.f;
        }
        l0 += p00 + p01;
        l1 += p10 + p11;
        psu0[j>>1] = pk2(p00, p01);
        psu1[j>>1] = pk2(p10, p11);
      }
      {                                   // P rows for t0 (lane) and t1 (64+lane), identity k-map
        uint4 u0 = make_uint4(psu0[0],psu0[1],psu0[2],psu0[3]);
        uint4 u1 = make_uint4(psu0[4],psu0[5],psu0[6],psu0[7]);
        uint4 u2 = make_uint4(psu1[0],psu1[1],psu1[2],psu1[3]);
        uint4 u3 = make_uint4(psu1[4],psu1[5],psu1[6],psu1[7]);
        *(uint4*)&Pl[lane*72 + w*16]           = u0;
        *(uint4*)&Pl[lane*72 + w*16 + 8]       = u1;
        *(uint4*)&Pl[(64+lane)*72 + w*16]      = u2;
        *(uint4*)&Pl[(64+lane)*72 + w*16 + 8]  = u3;
      }
      __syncthreads();                    // P complete
      // MFMA: A=vcT rows d; B half0 = Pl rows [16w,16w+16), half1 = rows [64+16w,..)
      #pragma unroll
      for (int ks=0; ks<2; ++ks){
        short8v bf0 = *(short8v*)&Pl [(16*w + (lane&15))*72      + ks*32 + (lane>>4)*8];
        short8v bf1 = *(short8v*)&Pl [(64 + 16*w + (lane&15))*72 + ks*32 + (lane>>4)*8];
        short8v a0  = *(short8v*)&vcT[(lane&15)*72               + ks*32 + (lane>>4)*8];
        short8v a1  = *(short8v*)&vcT[((lane&15)+16)*72          + ks*32 + (lane>>4)*8];
        acc0 = __builtin_amdgcn_mfma_f32_16x16x32_bf16(a0, bf0, acc0, 0, 0, 0);
        acc1 = __builtin_amdgcn_mfma_f32_16x16x32_bf16(a1, bf0, acc1, 0, 0, 0);
        acc2 = __builtin_amdgcn_mfma_f32_16x16x32_bf16(a0, bf1, acc2, 0, 0, 0);
        acc3 = __builtin_amdgcn_mfma_f32_16x16x32_bf16(a1, bf1, acc3, 0, 0, 0);
      }
    }
    meta[w*128 + lane]      = make_float4(l0, best0, __int_as_float(ibn0), 0.f);
    meta[w*128 + 64 + lane] = make_float4(l1, best1, __int_as_float(ibn1), 0.f);
  }
  __syncthreads();

  // ---- phase 2: lane handles tokens (which*64 + w*16 + c) for which in {0,1};
  //      lane m=lane>>4 owns d-set {4m..4m+3} u {16+4m..16+4m+3}; oc from acc regs.
  {
    int c = lane & 15, m = lane >> 4;
    int dA = 4*m, dB = 16 + 4*m;
    const float*  kb2 = qk + (size_t)b*SEQ*QKS + 256 + hh*DH;
    const ushort* vb2 = vg + (size_t)b*SEQ*VGS + hh*DH;
    #pragma unroll
    for (int which=0; which<2; ++which){
      int tokidx = which*64 + w*16 + c;
      int t = g*128 + tokidx;
      int own = t >> 2, nvis = (t+1) >> 2;
      float q8[8];
      {
        const float* qrow = qk + ((size_t)b*SEQ + t)*QKS + hh*DH;
        float4 a4 = *(const float4*)(qrow + dA);
        float4 b4 = *(const float4*)(qrow + dB);
        q8[0]=a4.x; q8[1]=a4.y; q8[2]=a4.z; q8[3]=a4.w;
        q8[4]=b4.x; q8[5]=b4.y; q8[6]=b4.z; q8[7]=b4.w;
      }
      float out8[8];
      #pragma unroll
      for (int j=0;j<4;j++){
        out8[j]   = which ? acc2[j] : acc0[j];
        out8[4+j] = which ? acc3[j] : acc1[j];
      }
      float ll = 0.f, bb = -1e30f;
      int bn = (own==0) ? 1 : 0;         // jax top_k fallback
      #pragma unroll
      for (int sp=0; sp<4; ++sp){
        float4 m4 = meta[sp*128 + tokidx];
        ll += m4.x;
        int mi = __float_as_int(m4.z);
        // tile-interleaved splits: equal scores resolve to the lower n
        if (m4.y > bb || (m4.y == bb && mi >= 0 && mi < bn)){ bb = m4.y; bn = mi; }
      }
      const ushort* gr = vg + ((size_t)b*SEQ + t)*VGS + 256;
      float g0 = sigmoidf_(bf2f(gr[hh])), g1 = sigmoidf_(bf2f(gr[8+hh])), g2 = sigmoidf_(bf2f(gr[16+hh]));
      float inv = (nvis > 0) ? g0/ll : 0.f;
      #pragma unroll
      for (int j=0;j<8;j++) out8[j] *= inv;

      // selection branch: own block + best block, causal token mask, d-split dots
      float s2[8];
      float m2 = -1e30f;
      #pragma unroll
      for (int ki=0; ki<8; ++ki){
        int tt = (ki<4 ? own : bn)*4 + (ki&3);
        float s = -1e30f;
        if (tt <= t){                     // uniform across the 4 lanes of this token
          const float* kr = kb2 + (size_t)tt*QKS;
          float4 a4 = *(const float4*)(kr + dA);
          float4 c4 = *(const float4*)(kr + dB);
          float ps = q8[0]*a4.x + q8[1]*a4.y + q8[2]*a4.z + q8[3]*a4.w
                   + q8[4]*c4.x + q8[5]*c4.y + q8[6]*c4.z + q8[7]*c4.w;
          ps += __shfl_xor(ps, 16);
          ps += __shfl_xor(ps, 32);
          s = ps*SCALE;
          m2 = fmaxf(m2, s);
        }
        s2[ki] = s;
      }
      float l2 = 0.f;
      #pragma unroll
      for (int ki=0; ki<8; ++ki)
        if (s2[ki] > -1e29f) l2 += __expf(s2[ki] - m2);
      float inv2 = g1/l2;                 // l2 >= 1 (self token always visible)
      #pragma unroll
      for (int ki=0; ki<8; ++ki){
        int tt = (ki<4 ? own : bn)*4 + (ki&3);
        if (tt <= t){
          float pw = __expf(s2[ki] - m2) * inv2;
          float fA[4], fB[4];
          bfu2_to_f32(*(const uint2*)(vb2 + (size_t)tt*VGS + dA), fA);
          bfu2_to_f32(*(const uint2*)(vb2 + (size_t)tt*VGS + dB), fB);
          #pragma unroll
          for (int j=0;j<4;j++){ out8[j] += pw*fA[j]; out8[4+j] += pw*fB[j]; }
        }
      }

      // sliding window (W=2): tokens t-1, t
      int tp = (t>0) ? t-1 : 0;
      float sa, sb;
      {
        const float* ka = kb2 + (size_t)tp*QKS;
        const float* kb4= kb2 + (size_t)t *QKS;
        float4 a0 = *(const float4*)(ka + dA), a1 = *(const float4*)(ka + dB);
        float4 b0 = *(const float4*)(kb4 + dA), b1 = *(const float4*)(kb4 + dB);
        float pa_ = q8[0]*a0.x + q8[1]*a0.y + q8[2]*a0.z + q8[3]*a0.w
                  + q8[4]*a1.x + q8[5]*a1.y + q8[6]*a1.z + q8[7]*a1.w;
        float pb_ = q8[0]*b0.x + q8[1]*b0.y + q8[2]*b0.z + q8[3]*b0.w
                  + q8[4]*b1.x + q8[5]*b1.y + q8[6]*b1.z + q8[7]*b1.w;
        pa_ += __shfl_xor(pa_, 16); pa_ += __shfl_xor(pa_, 32);
        pb_ += __shfl_xor(pb_, 16); pb_ += __shfl_xor(pb_, 32);
        sa = pa_*SCALE; sb = pb_*SCALE;
      }
      float m3 = (t>0) ? fmaxf(sa, sb) : sb;
      float pa = (t>0) ? __expf(sa-m3) : 0.f;
      float pb = __expf(sb-m3);
      float inv3 = g2/(pa+pb);
      float va[4], vaB[4], vbv[4], vbB[4];
      bfu2_to_f32(*(const uint2*)(vb2 + (size_t)tp*VGS + dA), va);
      bfu2_to_f32(*(const uint2*)(vb2 + (size_t)tp*VGS + dB), vaB);
      bfu2_to_f32(*(const uint2*)(vb2 + (size_t)t *VGS + dA), vbv);
      bfu2_to_f32(*(const uint2*)(vb2 + (size_t)t *VGS + dB), vbB);
      ushort* orow = o + ((size_t)b*SEQ + t)*DIM + hh*DH;
      float rrA[4], rrB[4];
      #pragma unroll
      for (int j=0;j<4;j++){
        rrA[j] = out8[j]   + (pa*va[j]  + pb*vbv[j])*inv3;
        rrB[j] = out8[4+j] + (pa*vaB[j] + pb*vbB[j])*inv3;
      }
      uint2 uA, uB;
      uA.x = pk2(rrA[0], rrA[1]); uA.y = pk2(rrA[2], rrA[3]);
      uB.x = pk2(rrB[0], rrB[1]); uB.y = pk2(rrB[2], rrB[3]);
      *(uint2*)&orow[dA] = uA;
      *(uint2*)&orow[dB] = uB;
    }
  }
}

extern "C" void kernel_launch(void* const* d_in, const int* in_sizes, int n_in,
                              void* d_out, int out_size, void* d_ws, size_t ws_size,
                              hipStream_t stream) {
  const float* x_in   = (const float*)d_in[0];
  const float* ln_a_g = (const float*)d_in[1];
  const float* ln_a_b = (const float*)d_in[2];
  const float* Wq     = (const float*)d_in[3];
  const float* Wk     = (const float*)d_in[4];
  const float* Wv     = (const float*)d_in[5];
  const float* Wg     = (const float*)d_in[6];
  const float* Wo     = (const float*)d_in[7];
  const float* ln_f_g = (const float*)d_in[8];
  const float* ln_f_b = (const float*)d_in[9];
  const float* W1     = (const float*)d_in[10];
  const float* b1     = (const float*)d_in[11];
  const float* W2     = (const float*)d_in[12];
  const float* b2     = (const float*)d_in[13];

  float* xout = (float*)d_out;             // running residual stream [8192][256] f32
  float* ws = (float*)d_ws;
  const size_t NTOK = (size_t)BATCH*SEQ;   // 8192
  float* h    = ws;                                    // [8192][256] f32
  float* qkb  = h    + NTOK*DIM;                       // [8192][512] f32
  float* kcb  = qkb  + NTOK*QKS;                       // [4][8][512][32] f32
  ushort* vctb = (ushort*)(kcb + (size_t)BATCH*NH*NB*DH);  // [4][8][32][512] bf16 (transposed)
  float* wqk  = (float*)(vctb + (size_t)BATCH*NH*NB*DH);   // [4][256][512] f32
  ushort* hb   = (ushort*)(wqk + (size_t)4*DIM*QKS);   // [8192][256] bf16
  ushort* vgu  = hb   + NTOK*DIM;                      // [8192][320] bf16
  ushort* obu  = vgu  + NTOK*VGS;                      // [8192][256] bf16
  ushort* midu = obu  + NTOK*DIM;                      // [8192][512] bf16
  ushort* wvgT = midu + NTOK*512;                      // [4][320][256] bf16
  ushort* woT  = wvgT + (size_t)4*VGS*DIM;             // [4][256][256] bf16
  ushort* w1T  = woT  + (size_t)4*DIM*DIM;             // [2][512][256] bf16
  ushort* w2T  = w1T  + (size_t)2*512*DIM;             // [2][256][512] bf16

  copy_f32<<<2048, 256, 0, stream>>>(x_in, xout, (int)(NTOK*DIM/4));
  build_wqk <<<(4*256*QKS+255)/256, 256, 0, stream>>>(Wq, Wk, wqk);
  build_wvgT<<<(4*VGS*256+255)/256, 256, 0, stream>>>(Wv, Wg, wvgT);
  build_wT  <<<(4*256*256+255)/256, 256, 0, stream>>>(Wo, woT, 4, 256, 256);
  build_wT  <<<(2*256*512+255)/256, 256, 0, stream>>>(W1, w1T, 2, 256, 512);
  build_wT  <<<(2*512*256+255)/256, 256, 0, stream>>>(W2, w2T, 2, 512, 256);

  dim3 gqk(64,8), gvg(64,5), g4(64,4), g8(64,8);
  for (int i=0;i<4;i++){
    ln_k<<<2048,256,0,stream>>>(xout, ln_a_g + i*DIM, ln_a_b + i*DIM, h, hb);
    gemm_f32<false,false,false><<<gqk,256,0,stream>>>(h, wqk + (size_t)i*DIM*QKS, nullptr, qkb, 8192,QKS,256);
    gemm_bf16<false,false,false,true><<<gvg,256,0,stream>>>(hb, wvgT + (size_t)i*VGS*DIM, nullptr, vgu, 8192,VGS,256);
    pool_k<<<2048,256,0,stream>>>(qkb, vgu, kcb, vctb);
    nsa_attn<<<512,256,0,stream>>>(qkb, vgu, kcb, vctb, obu);
    gemm_bf16<false,false,true,false><<<g4,256,0,stream>>>(obu, woT + (size_t)i*DIM*DIM, nullptr, xout, 8192,DIM,256);
    if (i & 1){
      int l = i >> 1;
      ln_k<<<2048,256,0,stream>>>(xout, ln_f_g + l*DIM, ln_f_b + l*DIM, h, hb);
      gemm_bf16<true,true,false,true><<<g8,256,0,stream>>>(hb,   w1T + (size_t)l*512*DIM, b1 + l*512, midu, 8192,512,256);
      gemm_bf16<true,false,true,false><<<g4,256,0,stream>>>(midu, w2T + (size_t)l*DIM*512, b2 + l*DIM, xout, 8192,DIM,512);
    }
  }
}

// Round 19
// 543.329 us; speedup vs baseline: 1.1129x; 1.0890x over previous
//
#include <hip/hip_runtime.h>
#include <hip/hip_bf16.h>
#include <math.h>

#define NH 8
#define DH 32
#define DIM 256
#define SEQ 2048
#define BATCH 4
#define NB 512            // SEQ / C
#define QKS 512           // q|k packed f32 row stride
#define VGS 320           // v|g packed bf16 row stride: 256 v | 24 g | 40 pad
#define SCALE 0.17677669529663687f  // DH^-0.5

typedef short short8v __attribute__((ext_vector_type(8)));
typedef float float4v __attribute__((ext_vector_type(4)));

__device__ __forceinline__ float sigmoidf_(float x){ return 1.f/(1.f+__expf(-x)); }
__device__ __forceinline__ ushort f2bf(float f){
  uint b = __float_as_uint(f);
  return (ushort)((b + 0x7fffu + ((b>>16)&1u)) >> 16);   // RNE
}
__device__ __forceinline__ float bf2f(ushort u){ return __uint_as_float(((uint)u)<<16); }
__device__ __forceinline__ float bflo(uint u){ return __uint_as_float(u<<16); }
__device__ __forceinline__ float bfhi(uint u){ return __uint_as_float(u & 0xffff0000u); }
__device__ __forceinline__ uint pk2(float a, float b){ return (uint)f2bf(a) | ((uint)f2bf(b)<<16); }
__device__ __forceinline__ void bfu4_to_f32(uint4 u, float* f){
  f[0]=bflo(u.x); f[1]=bfhi(u.x);
  f[2]=bflo(u.y); f[3]=bfhi(u.y);
  f[4]=bflo(u.z); f[5]=bfhi(u.z);
  f[6]=bflo(u.w); f[7]=bfhi(u.w);
}

// ---------------- copy (residual stream init) ----------------
__global__ void copy_f32(const float* __restrict__ in, float* __restrict__ out, int n4){
  int i = blockIdx.x*blockDim.x + threadIdx.x;
  if (i < n4) ((float4*)out)[i] = ((const float4*)in)[i];
}

// ---------------- weight packers ----------------
__global__ void build_wqk(const float* __restrict__ Wq, const float* __restrict__ Wk, float* __restrict__ out){
  int i = blockIdx.x*256 + threadIdx.x;          // 4*256*512
  if (i >= 4*256*QKS) return;
  int col = i & 511, rk = (i>>9)&255, l = i>>17;
  out[i] = (col < 256) ? Wq[((size_t)l*256+rk)*256+col] : Wk[((size_t)l*256+rk)*256+col-256];
}
__global__ void build_wvgT(const float* __restrict__ Wv, const float* __restrict__ Wg, ushort* __restrict__ out){
  int i = blockIdx.x*256 + threadIdx.x;          // 4*320*256 : out[l][n][k] = B[k][n]
  if (i >= 4*VGS*256) return;
  int k = i & 255, n = (i>>8)%VGS, l = i/(VGS*256);
  float v = 0.f;
  if      (n < 256) v = Wv[((size_t)l*256+k)*256+n];
  else if (n < 280) v = Wg[((size_t)l*256+k)*24 + (n-256)];
  out[i] = f2bf(v);
}
__global__ void build_wT(const float* __restrict__ in, ushort* __restrict__ out, int L, int K, int N){
  int i = blockIdx.x*256 + threadIdx.x;          // out[l][n][k] = in[l][k][n]
  if (i >= L*K*N) return;
  int k = i % K, n = (i/K) % N, l = i/(K*N);
  out[i] = f2bf(in[((size_t)l*K+k)*N+n]);
}

// ---------------- layernorm: one wave per row, dual f32+bf16 output ----------------
__global__ __launch_bounds__(256) void ln_k(const float* __restrict__ x, const float* __restrict__ g,
                                            const float* __restrict__ b, float* __restrict__ h,
                                            ushort* __restrict__ hb){
  int row  = blockIdx.x*4 + (threadIdx.x>>6);
  int lane = threadIdx.x & 63;
  int c = lane*4;
  const float* xr = x + (size_t)row*DIM + c;
  float4 v = *(const float4*)xr;
  float s = v.x+v.y+v.z+v.w;
  float q = v.x*v.x+v.y*v.y+v.z*v.z+v.w*v.w;
  #pragma unroll
  for (int off=32; off>0; off>>=1){ s += __shfl_xor(s, off); q += __shfl_xor(q, off); }
  float mean = s * (1.f/DIM);
  float var  = q * (1.f/DIM) - mean*mean;
  float rs = rsqrtf(var + 1e-5f);
  float4 gg = *(const float4*)(g + c);
  float4 bb = *(const float4*)(b + c);
  float4 o;
  o.x = (v.x-mean)*rs*gg.x + bb.x;
  o.y = (v.y-mean)*rs*gg.y + bb.y;
  o.z = (v.z-mean)*rs*gg.z + bb.z;
  o.w = (v.w-mean)*rs*gg.w + bb.w;
  *(float4*)(h + (size_t)row*DIM + c) = o;
  uint2 u;
  u.x = pk2(o.x, o.y);
  u.y = pk2(o.z, o.w);
  *(uint2*)&hb[(size_t)row*DIM + c] = u;
}

// ---------------- f32 GEMM (q|k path), guard-free, BK=32 ----------------
template<bool BIAS, bool LEAKY, bool ACC>
__global__ __launch_bounds__(256) void gemm_f32(const float* __restrict__ A, const float* __restrict__ B,
                                                const float* __restrict__ bias, float* __restrict__ C,
                                                int M, int N, int K){
  __shared__ float As[32][132];
  __shared__ float Bs[32][68];
  int tid = threadIdx.x;
  int m0 = blockIdx.x*128, n0 = blockIdx.y*64;
  int tx = tid & 15, ty = tid >> 4;
  int ar = tid >> 1;            // 0..127
  int ac = (tid & 1)*16;        // 0 or 16
  int bk = tid >> 3;            // 0..31
  int bn = (tid & 7)*8;         // 0..56
  const float* Ap = A + (size_t)(m0+ar)*K + ac;
  const float* Bp = B + (size_t)bk*N + n0 + bn;
  float4 apre[4], bpre[2];
  #pragma unroll
  for (int j=0;j<4;j++) apre[j] = *(const float4*)(Ap + 4*j);
  bpre[0] = *(const float4*)Bp;
  bpre[1] = *(const float4*)(Bp + 4);
  float acc[8][4];
  #pragma unroll
  for (int i=0;i<8;i++)
    #pragma unroll
    for (int j=0;j<4;j++) acc[i][j]=0.f;
  for (int k0=0; k0<K; k0+=32){
    #pragma unroll
    for (int j=0;j<4;j++){
      As[ac+4*j+0][ar]=apre[j].x; As[ac+4*j+1][ar]=apre[j].y;
      As[ac+4*j+2][ar]=apre[j].z; As[ac+4*j+3][ar]=apre[j].w;
    }
    *(float4*)&Bs[bk][bn]   = bpre[0];
    *(float4*)&Bs[bk][bn+4] = bpre[1];
    __syncthreads();
    if (k0 + 32 < K){
      #pragma unroll
      for (int j=0;j<4;j++) apre[j] = *(const float4*)(Ap + k0 + 32 + 4*j);
      bpre[0] = *(const float4*)(Bp + (size_t)(k0+32)*N);
      bpre[1] = *(const float4*)(Bp + (size_t)(k0+32)*N + 4);
    }
    #pragma unroll
    for (int kk=0;kk<32;kk++){
      float4 bv  = *(const float4*)&Bs[kk][tx*4];
      float4 av0 = *(const float4*)&As[kk][ty*8];
      float4 av1 = *(const float4*)&As[kk][ty*8+4];
      float av[8] = {av0.x,av0.y,av0.z,av0.w,av1.x,av1.y,av1.z,av1.w};
      float bw[4] = {bv.x,bv.y,bv.z,bv.w};
      #pragma unroll
      for (int i=0;i<8;i++)
        #pragma unroll
        for (int j=0;j<4;j++) acc[i][j] += av[i]*bw[j];
    }
    __syncthreads();
  }
  #pragma unroll
  for (int i=0;i<8;i++){
    int m = m0 + ty*8 + i;
    #pragma unroll
    for (int j=0;j<4;j++){
      int n = n0 + tx*4 + j;
      float val = acc[i][j];
      if (BIAS)  val += bias[n];
      if (LEAKY) val = val > 0.f ? val : 0.01f*val;
      float* cp = C + (size_t)m*N + n;
      if (ACC) val += *cp;
      *cp = val;
    }
  }
}

// ---------------- bf16 MFMA GEMM: C = act(A[M,K] @ Bt[N,K]^T + bias) ----------------
template<bool BIAS, bool LEAKY, bool ACC, bool OBF16>
__global__ __launch_bounds__(256) void gemm_bf16(const ushort* __restrict__ A, const ushort* __restrict__ Bt,
                                                 const float* __restrict__ bias, void* __restrict__ Cv,
                                                 int M, int N, int K){
  __shared__ ushort Al[128*64];
  __shared__ ushort Bl[64*64];
  int tid = threadIdx.x;
  int m0 = blockIdx.x*128, n0 = blockIdx.y*64;
  int w = tid>>6, lane = tid&63;
  int wm = w>>1, wn = w&1;
  float4v acc[4][2];
  #pragma unroll
  for (int i=0;i<4;i++)
    #pragma unroll
    for (int j=0;j<2;j++) acc[i][j] = (float4v){0.f,0.f,0.f,0.f};
  for (int k0=0; k0<K; k0+=64){
    #pragma unroll
    for (int i=0;i<4;i++){
      int id = tid + 256*i;
      int r = id>>3, c = id&7;
      *(uint4*)&Al[r*64 + ((c ^ (r&7))*8)] = *(const uint4*)&A[(size_t)(m0+r)*K + k0 + c*8];
    }
    #pragma unroll
    for (int i=0;i<2;i++){
      int id = tid + 256*i;
      int r = id>>3, c = id&7;
      *(uint4*)&Bl[r*64 + ((c ^ (r&7))*8)] = *(const uint4*)&Bt[(size_t)(n0+r)*K + k0 + c*8];
    }
    __syncthreads();
    #pragma unroll
    for (int kk=0; kk<2; ++kk){
      short8v a[4], bfr[2];
      #pragma unroll
      for (int mf=0; mf<4; mf++){
        int r = wm*64 + mf*16 + (lane&15);
        int c = (kk*4 + (lane>>4)) ^ (r&7);
        a[mf] = *(short8v*)&Al[r*64 + c*8];
      }
      #pragma unroll
      for (int nf=0; nf<2; nf++){
        int r = wn*32 + nf*16 + (lane&15);
        int c = (kk*4 + (lane>>4)) ^ (r&7);
        bfr[nf] = *(short8v*)&Bl[r*64 + c*8];
      }
      #pragma unroll
      for (int mf=0; mf<4; mf++)
        #pragma unroll
        for (int nf=0; nf<2; nf++)
          acc[mf][nf] = __builtin_amdgcn_mfma_f32_16x16x32_bf16(a[mf], bfr[nf], acc[mf][nf], 0, 0, 0);
    }
    __syncthreads();
  }
  #pragma unroll
  for (int nf=0; nf<2; nf++){
    int col = n0 + wn*32 + nf*16 + (lane&15);
    float bv = BIAS ? bias[col] : 0.f;
    #pragma unroll
    for (int mf=0; mf<4; mf++){
      #pragma unroll
      for (int r=0; r<4; r++){
        int row = m0 + wm*64 + mf*16 + (lane>>4)*4 + r;
        float vv = acc[mf][nf][r];
        if (BIAS) vv += bv;
        if (LEAKY) vv = vv > 0.f ? vv : 0.01f*vv;
        if (OBF16) ((ushort*)Cv)[(size_t)row*N + col] = f2bf(vv);
        else {
          float* C = (float*)Cv;
          if (ACC) vv += C[(size_t)row*N + col];
          C[(size_t)row*N + col] = vv;
        }
      }
    }
  }
}

// ---------------- mean-pool K/V blocks (C=4): kc [b][h][n][32] f32, vct [b][h][d][n] bf16 ----------------
__global__ void pool_k(const float* __restrict__ qk, const ushort* __restrict__ vg,
                       float* __restrict__ kc, ushort* __restrict__ vct){
  int i = blockIdx.x*256 + threadIdx.x;       // 0 .. B*H*NB*32-1
  if (i >= BATCH*NH*NB*DH) return;
  int d = i & 31, n = (i >> 5) & 511, h = (i >> 14) & 7, b = i >> 17;
  size_t kb = ((size_t)(b*SEQ + n*4))*QKS + 256 + h*DH + d;
  kc[i] = 0.25f*(qk[kb] + qk[kb+QKS] + qk[kb+2*QKS] + qk[kb+3*QKS]);
  size_t vb = ((size_t)(b*SEQ + n*4))*VGS + h*DH + d;
  float pv = 0.25f*(bf2f(vg[vb]) + bf2f(vg[vb+VGS]) + bf2f(vg[vb+2*VGS]) + bf2f(vg[vb+3*VGS]));
  vct[(((size_t)(b*NH + h))*DH + d)*NB + n] = f2bf(pv);   // transposed: MFMA-B-ready
}

// ---------------- fused NSA attention v10: f32 scores + MFMA P.Vc ----------------
// 32 groups x 64 tokens per (b,h). Grid 1024, 4 waves.
// Block e: hh=e&7 (XCD slot), b=(e>>3)&3, q=(e>>5)&7, r=e>>8;
//   g = {31-q, q, 23-q, 8+q}[r] -> bijective, per-CU weight ~constant, heavy first.
// Per 64-n tile: (1) stage kt f32 + vcT bf16 [d][n]; (2) score phase: wave w rows
//   [w*16,w*16+16), lane=token, EXACT grouped-4 f32 dot (argmax bitwise-preserved),
//   l/best/bn in f32, p -> bf16 into padded P_lds; (3) MFMA phase: wave w computes
//   oc for tokens [16w,16w+16) via mfma 16x16x32 bf16, A=P[tok][n], B=vcT[d][n]
//   (both k-minor, same mapping as proven gemm_bf16 -> HW k-permutation cancels;
//   C layout col=lane&15,row=(lane>>4)*4+reg, HW-verified).
// Phase 2: 4 lanes per token, d-split (8 dims each); oc read from ocl f32.
__global__ __launch_bounds__(256, 4) void nsa_attn(
    const float* __restrict__ qk, const ushort* __restrict__ vg,
    const float* __restrict__ kc, const ushort* __restrict__ vct,
    ushort* __restrict__ o)
{
  __shared__ float  kt[64*32];       // 8 KB f32 kc tile
  __shared__ ushort vcT[32*72];      // 4.5 KB bf16 Vc^T tile [d][n], pad 8
  __shared__ ushort Pl[64*72];       // 9 KB bf16 P tile [tok][n], pad 8
  __shared__ float  ocl[64*36];      // 9 KB f32 final oc [tok][d], pad 4
  __shared__ float4 meta[4*64];      // 4 KB (l, best, bestn, -)   -> ~35 KB
  int e = blockIdx.x;
  int hh = e & 7;
  int b  = (e >> 3) & 3;
  int qq = (e >> 5) & 7;
  int r  = e >> 8;
  int g  = (r==0) ? (31-qq) : (r==1) ? qq : (r==2) ? (23-qq) : (8+qq);
  int tid = threadIdx.x;
  int w = tid >> 6, lane = tid & 63;
  const float*  kcg  = kc  + ((size_t)(b*NH + hh)*NB)*DH;
  const ushort* vctg = vct + ((size_t)(b*NH + hh)*DH)*NB;

  // ---- phase 1
  {
    int t = g*64 + lane;
    int own = t >> 2, nvis = (t+1) >> 2;
    int nmax = 16*(g+1);                  // block-uniform visibility bound
    float qv[32];
    {
      const float4* qr = (const float4*)(qk + ((size_t)b*SEQ + t)*QKS + hh*DH);
      #pragma unroll
      for (int d8=0; d8<8; d8++){
        float4 a4 = qr[d8];
        qv[4*d8]=a4.x; qv[4*d8+1]=a4.y; qv[4*d8+2]=a4.z; qv[4*d8+3]=a4.w;
      }
    }
    float l = 0.f, best = -1e30f;
    int bn1 = -1;
    float4v acc0 = (float4v){0.f,0.f,0.f,0.f};
    float4v acc1 = (float4v){0.f,0.f,0.f,0.f};

    int tiles = (g + 4) >> 2;             // ceil(16(g+1)/64)
    for (int ti=0; ti<tiles; ++ti){
      int base = ti*64;
      if (ti) __syncthreads();            // prev tile's MFMA reads done
      {                                   // stage kt (2 float4/thr) + vcT (1 uint4/thr, [d][n])
        const float4* sk = (const float4*)(kcg + (size_t)base*DH);
        ((float4*)kt)[tid]     = sk[tid];
        ((float4*)kt)[tid+256] = sk[tid+256];
        int sd = tid >> 3, sn = (tid & 7)*8;
        *(uint4*)&vcT[sd*72 + sn] = *(const uint4*)&vctg[(size_t)sd*NB + base + sn];
      }
      __syncthreads();
      // score phase: wave w owns rows [w*16, w*16+16)
      float ps[16];
      #pragma unroll
      for (int j=0; j<16; ++j){
        int rr = w*16 + j;
        int n = base + rr;
        float p = 0.f;
        if (n < nmax){                    // wave-uniform
          const float4* kp = (const float4*)&kt[rr*32];
          float s = 0.f;
          #pragma unroll
          for (int d8=0; d8<8; d8++){     // exact grouped-4 ordering: argmax-stable
            float4 k4 = kp[d8];
            s += qv[4*d8]*k4.x + qv[4*d8+1]*k4.y + qv[4*d8+2]*k4.z + qv[4*d8+3]*k4.w;
          }
          s *= SCALE;
          bool act = (n < nvis);
          if (act && n != own && s > best){ best = s; bn1 = n; }  // ascending n in-wave
          p = act ? __expf(s) : 0.f;      // max-free: |s| small, exp safe
          l += p;
        }
        ps[j] = p;
      }
      {                                   // P[lane][w*16..+16] as 2x b128
        uint4 u0, u1;
        u0.x = pk2(ps[0],ps[1]);  u0.y = pk2(ps[2],ps[3]);
        u0.z = pk2(ps[4],ps[5]);  u0.w = pk2(ps[6],ps[7]);
        u1.x = pk2(ps[8],ps[9]);  u1.y = pk2(ps[10],ps[11]);
        u1.z = pk2(ps[12],ps[13]);u1.w = pk2(ps[14],ps[15]);
        *(uint4*)&Pl[lane*72 + w*16]     = u0;
        *(uint4*)&Pl[lane*72 + w*16 + 8] = u1;
      }
      __syncthreads();                    // P complete
      // MFMA phase: wave w -> tokens [16w, 16w+16), full 64-n K via 2 ksteps
      #pragma unroll
      for (int ks=0; ks<2; ++ks){
        short8v a  = *(short8v*)&Pl [(16*w + (lane&15))*72 + ks*32 + (lane>>4)*8];
        short8v b0 = *(short8v*)&vcT[(lane&15)*72        + ks*32 + (lane>>4)*8];
        short8v b1 = *(short8v*)&vcT[((lane&15)+16)*72   + ks*32 + (lane>>4)*8];
        acc0 = __builtin_amdgcn_mfma_f32_16x16x32_bf16(a, b0, acc0, 0, 0, 0);
        acc1 = __builtin_amdgcn_mfma_f32_16x16x32_bf16(a, b1, acc1, 0, 0, 0);
      }
    }
    // write oc (f32) + meta
    #pragma unroll
    for (int r2=0; r2<4; ++r2){
      int token = 16*w + (lane>>4)*4 + r2;
      ocl[token*36 + (lane&15)]      = acc0[r2];
      ocl[token*36 + 16 + (lane&15)] = acc1[r2];
    }
    meta[w*64 + lane] = make_float4(l, best, __int_as_float(bn1), 0.f);
  }
  __syncthreads();

  // ---- phase 2: 4 lanes per token, d-split (8 dims per lane)
  {
    int tok = tid >> 2;
    int ds  = (tid & 3)*8;
    int t = g*64 + tok;
    int own = t >> 2, nvis = (t+1) >> 2;
    float q8[8];
    {
      const float4* qr = (const float4*)(qk + ((size_t)b*SEQ + t)*QKS + hh*DH + ds);
      float4 a4 = qr[0], b4 = qr[1];
      q8[0]=a4.x; q8[1]=a4.y; q8[2]=a4.z; q8[3]=a4.w;
      q8[4]=b4.x; q8[5]=b4.y; q8[6]=b4.z; q8[7]=b4.w;
    }
    float out8[8];
    {
      float4 oA = *(const float4*)&ocl[tok*36 + ds];
      float4 oB = *(const float4*)&ocl[tok*36 + ds + 4];
      out8[0]=oA.x; out8[1]=oA.y; out8[2]=oA.z; out8[3]=oA.w;
      out8[4]=oB.x; out8[5]=oB.y; out8[6]=oB.z; out8[7]=oB.w;
    }
    float ll = 0.f, bb = -1e30f;
    int bn = (own==0) ? 1 : 0;         // jax top_k fallback
    #pragma unroll
    for (int sp=0; sp<4; ++sp){
      float4 m4 = meta[sp*64 + tok];
      ll += m4.x;
      int mi = __float_as_int(m4.z);
      // equal scores resolve to the lower n (mi>=0 excludes empty partials)
      if (m4.y > bb || (m4.y == bb && mi >= 0 && mi < bn)){ bb = m4.y; bn = mi; }
    }
    const ushort* gr = vg + ((size_t)b*SEQ + t)*VGS + 256;
    float g0 = sigmoidf_(bf2f(gr[hh])), g1 = sigmoidf_(bf2f(gr[8+hh])), g2 = sigmoidf_(bf2f(gr[16+hh]));
    float inv = (nvis > 0) ? g0/ll : 0.f;
    #pragma unroll
    for (int j=0;j<8;j++) out8[j] *= inv;

    // selection branch: own block + best block, causal token mask, d-split dots
    const float*  kb2 = qk + (size_t)b*SEQ*QKS + 256 + hh*DH + ds;
    const ushort* vb2 = vg + (size_t)b*SEQ*VGS + hh*DH + ds;
    float s2[8];
    float m2 = -1e30f;
    #pragma unroll
    for (int ki=0; ki<8; ++ki){
      int tt = (ki<4 ? own : bn)*4 + (ki&3);
      float s = -1e30f;
      if (tt <= t){                       // uniform across the 4 lanes of this token
        const float4* kr = (const float4*)(kb2 + (size_t)tt*QKS);
        float4 a4 = kr[0], c4 = kr[1];
        float ps = q8[0]*a4.x + q8[1]*a4.y + q8[2]*a4.z + q8[3]*a4.w
                 + q8[4]*c4.x + q8[5]*c4.y + q8[6]*c4.z + q8[7]*c4.w;
        ps += __shfl_xor(ps, 1);
        ps += __shfl_xor(ps, 2);
        s = ps*SCALE;
        m2 = fmaxf(m2, s);
      }
      s2[ki] = s;
    }
    float l2 = 0.f;
    #pragma unroll
    for (int ki=0; ki<8; ++ki)
      if (s2[ki] > -1e29f) l2 += __expf(s2[ki] - m2);
    float inv2 = g1/l2;                   // l2 >= 1 (self token always visible)
    #pragma unroll
    for (int ki=0; ki<8; ++ki){
      int tt = (ki<4 ? own : bn)*4 + (ki&3);
      if (tt <= t){
        float pw = __expf(s2[ki] - m2) * inv2;
        uint4 u = *(const uint4*)(vb2 + (size_t)tt*VGS);
        float f[8]; bfu4_to_f32(u, f);
        #pragma unroll
        for (int j=0;j<8;j++) out8[j] += pw*f[j];
      }
    }

    // sliding window (W=2): tokens t-1, t
    int tp = (t>0) ? t-1 : 0;
    float sa, sb;
    {
      const float4* ka = (const float4*)(kb2 + (size_t)tp*QKS);
      const float4* kb4= (const float4*)(kb2 + (size_t)t *QKS);
      float4 a0 = ka[0], a1 = ka[1], b0 = kb4[0], b1 = kb4[1];
      float pa_ = q8[0]*a0.x + q8[1]*a0.y + q8[2]*a0.z + q8[3]*a0.w
                + q8[4]*a1.x + q8[5]*a1.y + q8[6]*a1.z + q8[7]*a1.w;
      float pb_ = q8[0]*b0.x + q8[1]*b0.y + q8[2]*b0.z + q8[3]*b0.w
                + q8[4]*b1.x + q8[5]*b1.y + q8[6]*b1.z + q8[7]*b1.w;
      pa_ += __shfl_xor(pa_, 1); pa_ += __shfl_xor(pa_, 2);
      pb_ += __shfl_xor(pb_, 1); pb_ += __shfl_xor(pb_, 2);
      sa = pa_*SCALE; sb = pb_*SCALE;
    }
    float m3 = (t>0) ? fmaxf(sa, sb) : sb;
    float pa = (t>0) ? __expf(sa-m3) : 0.f;
    float pb = __expf(sb-m3);
    float inv3 = g2/(pa+pb);
    float va[8], vbv[8];
    bfu4_to_f32(*(const uint4*)(vb2 + (size_t)tp*VGS), va);
    bfu4_to_f32(*(const uint4*)(vb2 + (size_t)t *VGS), vbv);
    ushort* orow = o + ((size_t)b*SEQ + t)*DIM + hh*DH + ds;
    float rr[8];
    #pragma unroll
    for (int j=0;j<8;j++) rr[j] = out8[j] + (pa*va[j] + pb*vbv[j])*inv3;
    uint4 u;
    u.x = pk2(rr[0], rr[1]);
    u.y = pk2(rr[2], rr[3]);
    u.z = pk2(rr[4], rr[5]);
    u.w = pk2(rr[6], rr[7]);
    *(uint4*)orow = u;
  }
}

extern "C" void kernel_launch(void* const* d_in, const int* in_sizes, int n_in,
                              void* d_out, int out_size, void* d_ws, size_t ws_size,
                              hipStream_t stream) {
  const float* x_in   = (const float*)d_in[0];
  const float* ln_a_g = (const float*)d_in[1];
  const float* ln_a_b = (const float*)d_in[2];
  const float* Wq     = (const float*)d_in[3];
  const float* Wk     = (const float*)d_in[4];
  const float* Wv     = (const float*)d_in[5];
  const float* Wg     = (const float*)d_in[6];
  const float* Wo     = (const float*)d_in[7];
  const float* ln_f_g = (const float*)d_in[8];
  const float* ln_f_b = (const float*)d_in[9];
  const float* W1     = (const float*)d_in[10];
  const float* b1     = (const float*)d_in[11];
  const float* W2     = (const float*)d_in[12];
  const float* b2     = (const float*)d_in[13];

  float* xout = (float*)d_out;             // running residual stream [8192][256] f32
  float* ws = (float*)d_ws;
  const size_t NTOK = (size_t)BATCH*SEQ;   // 8192
  float* h    = ws;                                    // [8192][256] f32
  float* qkb  = h    + NTOK*DIM;                       // [8192][512] f32
  float* kcb  = qkb  + NTOK*QKS;                       // [4][8][512][32] f32
  ushort* vctb = (ushort*)(kcb + (size_t)BATCH*NH*NB*DH);  // [4][8][32][512] bf16 (transposed)
  float* wqk  = (float*)(vctb + (size_t)BATCH*NH*NB*DH);   // [4][256][512] f32
  ushort* hb   = (ushort*)(wqk + (size_t)4*DIM*QKS);   // [8192][256] bf16
  ushort* vgu  = hb   + NTOK*DIM;                      // [8192][320] bf16
  ushort* obu  = vgu  + NTOK*VGS;                      // [8192][256] bf16
  ushort* midu = obu  + NTOK*DIM;                      // [8192][512] bf16
  ushort* wvgT = midu + NTOK*512;                      // [4][320][256] bf16
  ushort* woT  = wvgT + (size_t)4*VGS*DIM;             // [4][256][256] bf16
  ushort* w1T  = woT  + (size_t)4*DIM*DIM;             // [2][512][256] bf16
  ushort* w2T  = w1T  + (size_t)2*512*DIM;             // [2][256][512] bf16

  copy_f32<<<2048, 256, 0, stream>>>(x_in, xout, (int)(NTOK*DIM/4));
  build_wqk <<<(4*256*QKS+255)/256, 256, 0, stream>>>(Wq, Wk, wqk);
  build_wvgT<<<(4*VGS*256+255)/256, 256, 0, stream>>>(Wv, Wg, wvgT);
  build_wT  <<<(4*256*256+255)/256, 256, 0, stream>>>(Wo, woT, 4, 256, 256);
  build_wT  <<<(2*256*512+255)/256, 256, 0, stream>>>(W1, w1T, 2, 256, 512);
  build_wT  <<<(2*512*256+255)/256, 256, 0, stream>>>(W2, w2T, 2, 512, 256);

  dim3 gqk(64,8), gvg(64,5), g4(64,4), g8(64,8);
  for (int i=0;i<4;i++){
    ln_k<<<2048,256,0,stream>>>(xout, ln_a_g + i*DIM, ln_a_b + i*DIM, h, hb);
    gemm_f32<false,false,false><<<gqk,256,0,stream>>>(h, wqk + (size_t)i*DIM*QKS, nullptr, qkb, 8192,QKS,256);
    gemm_bf16<false,false,false,true><<<gvg,256,0,stream>>>(hb, wvgT + (size_t)i*VGS*DIM, nullptr, vgu, 8192,VGS,256);
    pool_k<<<2048,256,0,stream>>>(qkb, vgu, kcb, vctb);
    nsa_attn<<<1024,256,0,stream>>>(qkb, vgu, kcb, vctb, obu);
    gemm_bf16<false,false,true,false><<<g4,256,0,stream>>>(obu, woT + (size_t)i*DIM*DIM, nullptr, xout, 8192,DIM,256);
    if (i & 1){
      int l = i >> 1;
      ln_k<<<2048,256,0,stream>>>(xout, ln_f_g + l*DIM, ln_f_b + l*DIM, h, hb);
      gemm_bf16<true,true,false,true><<<g8,256,0,stream>>>(hb,   w1T + (size_t)l*512*DIM, b1 + l*512, midu, 8192,512,256);
      gemm_bf16<true,false,true,false><<<g4,256,0,stream>>>(midu, w2T + (size_t)l*DIM*512, b2 + l*DIM, xout, 8192,DIM,512);
    }
  }
}

// Round 20
// 507.532 us; speedup vs baseline: 1.1914x; 1.0705x over previous
//
#include <hip/hip_runtime.h>
#include <hip/hip_bf16.h>
#include <math.h>

#define NH 8
#define DH 32
#define DIM 256
#define SEQ 2048
#define BATCH 4
#define NB 512            // SEQ / C
#define QKS 512           // q|k packed f32 row stride
#define VGS 320           // v|g packed bf16 row stride: 256 v | 24 g | 40 pad
#define SCALE 0.17677669529663687f  // DH^-0.5

typedef short short8v __attribute__((ext_vector_type(8)));
typedef float float4v __attribute__((ext_vector_type(4)));

__device__ __forceinline__ float sigmoidf_(float x){ return 1.f/(1.f+__expf(-x)); }
__device__ __forceinline__ ushort f2bf(float f){
  uint b = __float_as_uint(f);
  return (ushort)((b + 0x7fffu + ((b>>16)&1u)) >> 16);   // RNE
}
__device__ __forceinline__ float bf2f(ushort u){ return __uint_as_float(((uint)u)<<16); }
__device__ __forceinline__ float bflo(uint u){ return __uint_as_float(u<<16); }
__device__ __forceinline__ float bfhi(uint u){ return __uint_as_float(u & 0xffff0000u); }
__device__ __forceinline__ uint pk2(float a, float b){ return (uint)f2bf(a) | ((uint)f2bf(b)<<16); }
__device__ __forceinline__ void bfu4_to_f32(uint4 u, float* f){
  f[0]=bflo(u.x); f[1]=bfhi(u.x);
  f[2]=bflo(u.y); f[3]=bfhi(u.y);
  f[4]=bflo(u.z); f[5]=bfhi(u.z);
  f[6]=bflo(u.w); f[7]=bfhi(u.w);
}

// ---------------- copy (residual stream init) ----------------
__global__ void copy_f32(const float* __restrict__ in, float* __restrict__ out, int n4){
  int i = blockIdx.x*blockDim.x + threadIdx.x;
  if (i < n4) ((float4*)out)[i] = ((const float4*)in)[i];
}

// ---------------- weight packers ----------------
__global__ void build_wqk(const float* __restrict__ Wq, const float* __restrict__ Wk, float* __restrict__ out){
  int i = blockIdx.x*256 + threadIdx.x;          // 4*256*512
  if (i >= 4*256*QKS) return;
  int col = i & 511, rk = (i>>9)&255, l = i>>17;
  out[i] = (col < 256) ? Wq[((size_t)l*256+rk)*256+col] : Wk[((size_t)l*256+rk)*256+col-256];
}
__global__ void build_wvgT(const float* __restrict__ Wv, const float* __restrict__ Wg, ushort* __restrict__ out){
  int i = blockIdx.x*256 + threadIdx.x;          // 4*320*256 : out[l][n][k] = B[k][n]
  if (i >= 4*VGS*256) return;
  int k = i & 255, n = (i>>8)%VGS, l = i/(VGS*256);
  float v = 0.f;
  if      (n < 256) v = Wv[((size_t)l*256+k)*256+n];
  else if (n < 280) v = Wg[((size_t)l*256+k)*24 + (n-256)];
  out[i] = f2bf(v);
}
__global__ void build_wT(const float* __restrict__ in, ushort* __restrict__ out, int L, int K, int N){
  int i = blockIdx.x*256 + threadIdx.x;          // out[l][n][k] = in[l][k][n]
  if (i >= L*K*N) return;
  int k = i % K, n = (i/K) % N, l = i/(K*N);
  out[i] = f2bf(in[((size_t)l*K+k)*N+n]);
}

// ---------------- layernorm: one wave per row, dual f32+bf16 output ----------------
__global__ __launch_bounds__(256) void ln_k(const float* __restrict__ x, const float* __restrict__ g,
                                            const float* __restrict__ b, float* __restrict__ h,
                                            ushort* __restrict__ hb){
  int row  = blockIdx.x*4 + (threadIdx.x>>6);
  int lane = threadIdx.x & 63;
  int c = lane*4;
  const float* xr = x + (size_t)row*DIM + c;
  float4 v = *(const float4*)xr;
  float s = v.x+v.y+v.z+v.w;
  float q = v.x*v.x+v.y*v.y+v.z*v.z+v.w*v.w;
  #pragma unroll
  for (int off=32; off>0; off>>=1){ s += __shfl_xor(s, off); q += __shfl_xor(q, off); }
  float mean = s * (1.f/DIM);
  float var  = q * (1.f/DIM) - mean*mean;
  float rs = rsqrtf(var + 1e-5f);
  float4 gg = *(const float4*)(g + c);
  float4 bb = *(const float4*)(b + c);
  float4 o;
  o.x = (v.x-mean)*rs*gg.x + bb.x;
  o.y = (v.y-mean)*rs*gg.y + bb.y;
  o.z = (v.z-mean)*rs*gg.z + bb.z;
  o.w = (v.w-mean)*rs*gg.w + bb.w;
  *(float4*)(h + (size_t)row*DIM + c) = o;
  uint2 u;
  u.x = pk2(o.x, o.y);
  u.y = pk2(o.z, o.w);
  *(uint2*)&hb[(size_t)row*DIM + c] = u;
}

// ---------------- fused projection: qk f32 GEMM + vg bf16 MFMA GEMM + pooling ----------------
// grid (64, 13): y<8 -> f32 block computing qk cols [64y,64y+64) with kc-pool epilogue
// (bitwise = pool_k: same add order on same f32 values); y>=8 -> bf16 MFMA block
// computing vg cols [64(y-8),..) with vct-pool epilogue (replicates bf16 round->mean).
// VALU-bound f32 blocks and MFMA-bound bf16 blocks co-schedule on the same CUs.
__global__ __launch_bounds__(256) void gemm_qkvg(
    const float* __restrict__ hA, const ushort* __restrict__ hbA,
    const float* __restrict__ Bqk, const ushort* __restrict__ BvgT,
    float* __restrict__ qkb, ushort* __restrict__ vgu,
    float* __restrict__ kcb, ushort* __restrict__ vctb){
  __shared__ __align__(16) char smem[25600];
  int tid = threadIdx.x;
  int m0 = blockIdx.x*128;
  if (blockIdx.y < 8){
    // ---------- f32 path (qk), tile 128x64, BK=32, 8x4/thread ----------
    float (*As)[132] = (float(*)[132])smem;            // 16896 B
    float (*Bs)[68]  = (float(*)[68])(smem + 16896);   //  8704 B
    int n0 = blockIdx.y*64;
    int tx = tid & 15, tyy = tid >> 4;
    int ar = tid >> 1;
    int ac = (tid & 1)*16;
    int bk = tid >> 3;
    int bn = (tid & 7)*8;
    const float* Ap = hA + (size_t)(m0+ar)*256 + ac;
    const float* Bp = Bqk + (size_t)bk*QKS + n0 + bn;
    float4 apre[4], bpre[2];
    #pragma unroll
    for (int j=0;j<4;j++) apre[j] = *(const float4*)(Ap + 4*j);
    bpre[0] = *(const float4*)Bp;
    bpre[1] = *(const float4*)(Bp + 4);
    float acc[8][4];
    #pragma unroll
    for (int i=0;i<8;i++)
      #pragma unroll
      for (int j=0;j<4;j++) acc[i][j]=0.f;
    for (int k0=0; k0<256; k0+=32){
      #pragma unroll
      for (int j=0;j<4;j++){
        As[ac+4*j+0][ar]=apre[j].x; As[ac+4*j+1][ar]=apre[j].y;
        As[ac+4*j+2][ar]=apre[j].z; As[ac+4*j+3][ar]=apre[j].w;
      }
      *(float4*)&Bs[bk][bn]   = bpre[0];
      *(float4*)&Bs[bk][bn+4] = bpre[1];
      __syncthreads();
      if (k0 + 32 < 256){
        #pragma unroll
        for (int j=0;j<4;j++) apre[j] = *(const float4*)(Ap + k0 + 32 + 4*j);
        bpre[0] = *(const float4*)(Bp + (size_t)(k0+32)*QKS);
        bpre[1] = *(const float4*)(Bp + (size_t)(k0+32)*QKS + 4);
      }
      #pragma unroll
      for (int kk=0;kk<32;kk++){
        float4 bv  = *(const float4*)&Bs[kk][tx*4];
        float4 av0 = *(const float4*)&As[kk][tyy*8];
        float4 av1 = *(const float4*)&As[kk][tyy*8+4];
        float av[8] = {av0.x,av0.y,av0.z,av0.w,av1.x,av1.y,av1.z,av1.w};
        float bw[4] = {bv.x,bv.y,bv.z,bv.w};
        #pragma unroll
        for (int i=0;i<8;i++)
          #pragma unroll
          for (int j=0;j<4;j++) acc[i][j] += av[i]*bw[j];
      }
      __syncthreads();
    }
    #pragma unroll
    for (int i=0;i<8;i++){
      int m = m0 + tyy*8 + i;
      #pragma unroll
      for (int j=0;j<4;j++)
        qkb[(size_t)m*QKS + n0 + tx*4 + j] = acc[i][j];
    }
    // kc pooling (cols >= 256): 0.25*(((k0+k1)+k2)+k3), same order/values as pool_k
    if (n0 >= 256){
      #pragma unroll
      for (int G=0; G<2; ++G){
        int row = m0 + tyy*8 + 4*G;
        int bi = row >> 11;                 // /2048
        int np = (row & 2047) >> 2;
        #pragma unroll
        for (int j=0;j<4;j++){
          int col = n0 + tx*4 + j - 256;    // 0..255
          int h_ = col >> 5, d = col & 31;
          float pv = 0.25f*(((acc[4*G][j] + acc[4*G+1][j]) + acc[4*G+2][j]) + acc[4*G+3][j]);
          kcb[(((size_t)(bi*NH + h_))*NB + np)*DH + d] = pv;
        }
      }
    }
  } else {
    // ---------- bf16 MFMA path (vg), tile 128x64, BK=64 ----------
    ushort* Al = (ushort*)smem;            // 16384 B
    ushort* Bl = (ushort*)(smem + 16384);  //  8192 B
    int n0 = (blockIdx.y - 8)*64;
    int w = tid>>6, lane = tid&63;
    int wm = w>>1, wn = w&1;
    float4v acc[4][2];
    #pragma unroll
    for (int i=0;i<4;i++)
      #pragma unroll
      for (int j=0;j<2;j++) acc[i][j] = (float4v){0.f,0.f,0.f,0.f};
    for (int k0=0; k0<256; k0+=64){
      #pragma unroll
      for (int i=0;i<4;i++){
        int id = tid + 256*i;
        int r = id>>3, c = id&7;
        *(uint4*)&Al[r*64 + ((c ^ (r&7))*8)] = *(const uint4*)&hbA[(size_t)(m0+r)*256 + k0 + c*8];
      }
      #pragma unroll
      for (int i=0;i<2;i++){
        int id = tid + 256*i;
        int r = id>>3, c = id&7;
        *(uint4*)&Bl[r*64 + ((c ^ (r&7))*8)] = *(const uint4*)&BvgT[(size_t)(n0+r)*256 + k0 + c*8];
      }
      __syncthreads();
      #pragma unroll
      for (int kk=0; kk<2; ++kk){
        short8v a[4], bfr[2];
        #pragma unroll
        for (int mf=0; mf<4; mf++){
          int r = wm*64 + mf*16 + (lane&15);
          int c = (kk*4 + (lane>>4)) ^ (r&7);
          a[mf] = *(short8v*)&Al[r*64 + c*8];
        }
        #pragma unroll
        for (int nf=0; nf<2; nf++){
          int r = wn*32 + nf*16 + (lane&15);
          int c = (kk*4 + (lane>>4)) ^ (r&7);
          bfr[nf] = *(short8v*)&Bl[r*64 + c*8];
        }
        #pragma unroll
        for (int mf=0; mf<4; mf++)
          #pragma unroll
          for (int nf=0; nf<2; nf++)
            acc[mf][nf] = __builtin_amdgcn_mfma_f32_16x16x32_bf16(a[mf], bfr[nf], acc[mf][nf], 0, 0, 0);
      }
      __syncthreads();
    }
    #pragma unroll
    for (int nf=0; nf<2; nf++){
      int col = n0 + wn*32 + nf*16 + (lane&15);
      #pragma unroll
      for (int mf=0; mf<4; mf++){
        ushort s4[4];
        #pragma unroll
        for (int r=0; r<4; r++){
          int row = m0 + wm*64 + mf*16 + (lane>>4)*4 + r;
          s4[r] = f2bf(acc[mf][nf][r]);
          vgu[(size_t)row*VGS + col] = s4[r];
        }
        if (col < 256){                      // vct pooling: bf16 round -> sequential mean
          int row0 = m0 + wm*64 + mf*16 + (lane>>4)*4;
          int bi = row0 >> 11;
          int np = (row0 & 2047) >> 2;
          float pv = 0.25f*(((bf2f(s4[0]) + bf2f(s4[1])) + bf2f(s4[2])) + bf2f(s4[3]));
          int h_ = col >> 5, d = col & 31;
          vctb[(((size_t)(bi*NH + h_))*DH + d)*NB + np] = f2bf(pv);
        }
      }
    }
  }
}

// ---------------- bf16 MFMA GEMM: C = act(A[M,K] @ Bt[N,K]^T + bias) ----------------
template<bool BIAS, bool LEAKY, bool ACC, bool OBF16>
__global__ __launch_bounds__(256) void gemm_bf16(const ushort* __restrict__ A, const ushort* __restrict__ Bt,
                                                 const float* __restrict__ bias, void* __restrict__ Cv,
                                                 int M, int N, int K){
  __shared__ ushort Al[128*64];
  __shared__ ushort Bl[64*64];
  int tid = threadIdx.x;
  int m0 = blockIdx.x*128, n0 = blockIdx.y*64;
  int w = tid>>6, lane = tid&63;
  int wm = w>>1, wn = w&1;
  float4v acc[4][2];
  #pragma unroll
  for (int i=0;i<4;i++)
    #pragma unroll
    for (int j=0;j<2;j++) acc[i][j] = (float4v){0.f,0.f,0.f,0.f};
  for (int k0=0; k0<K; k0+=64){
    #pragma unroll
    for (int i=0;i<4;i++){
      int id = tid + 256*i;
      int r = id>>3, c = id&7;
      *(uint4*)&Al[r*64 + ((c ^ (r&7))*8)] = *(const uint4*)&A[(size_t)(m0+r)*K + k0 + c*8];
    }
    #pragma unroll
    for (int i=0;i<2;i++){
      int id = tid + 256*i;
      int r = id>>3, c = id&7;
      *(uint4*)&Bl[r*64 + ((c ^ (r&7))*8)] = *(const uint4*)&Bt[(size_t)(n0+r)*K + k0 + c*8];
    }
    __syncthreads();
    #pragma unroll
    for (int kk=0; kk<2; ++kk){
      short8v a[4], bfr[2];
      #pragma unroll
      for (int mf=0; mf<4; mf++){
        int r = wm*64 + mf*16 + (lane&15);
        int c = (kk*4 + (lane>>4)) ^ (r&7);
        a[mf] = *(short8v*)&Al[r*64 + c*8];
      }
      #pragma unroll
      for (int nf=0; nf<2; nf++){
        int r = wn*32 + nf*16 + (lane&15);
        int c = (kk*4 + (lane>>4)) ^ (r&7);
        bfr[nf] = *(short8v*)&Bl[r*64 + c*8];
      }
      #pragma unroll
      for (int mf=0; mf<4; mf++)
        #pragma unroll
        for (int nf=0; nf<2; nf++)
          acc[mf][nf] = __builtin_amdgcn_mfma_f32_16x16x32_bf16(a[mf], bfr[nf], acc[mf][nf], 0, 0, 0);
    }
    __syncthreads();
  }
  #pragma unroll
  for (int nf=0; nf<2; nf++){
    int col = n0 + wn*32 + nf*16 + (lane&15);
    float bv = BIAS ? bias[col] : 0.f;
    #pragma unroll
    for (int mf=0; mf<4; mf++){
      #pragma unroll
      for (int r=0; r<4; r++){
        int row = m0 + wm*64 + mf*16 + (lane>>4)*4 + r;
        float vv = acc[mf][nf][r];
        if (BIAS) vv += bv;
        if (LEAKY) vv = vv > 0.f ? vv : 0.01f*vv;
        if (OBF16) ((ushort*)Cv)[(size_t)row*N + col] = f2bf(vv);
        else {
          float* C = (float*)Cv;
          if (ACC) vv += C[(size_t)row*N + col];
          C[(size_t)row*N + col] = vv;
        }
      }
    }
  }
}

// ---------------- fused NSA attention v10: f32 scores + MFMA P.Vc ----------------
// 32 groups x 64 tokens per (b,h). Grid 1024, 4 waves.
// Block e: hh=e&7 (XCD slot), b=(e>>3)&3, q=(e>>5)&7, r=e>>8;
//   g = {31-q, q, 23-q, 8+q}[r] -> bijective, per-CU weight ~constant, heavy first.
// Per 64-n tile: (1) stage kt f32 + vcT bf16 [d][n]; (2) score phase: wave w rows
//   [w*16,w*16+16), lane=token, EXACT grouped-4 f32 dot (argmax bitwise-preserved),
//   l/best/bn in f32, p -> bf16 into padded P_lds; (3) MFMA phase: wave w computes
//   oc for tokens [16w,16w+16) via mfma 16x16x32 bf16, A=P[tok][n], B=vcT[d][n].
// Phase 2: 4 lanes per token, d-split (8 dims each); oc read from ocl f32.
__global__ __launch_bounds__(256, 4) void nsa_attn(
    const float* __restrict__ qk, const ushort* __restrict__ vg,
    const float* __restrict__ kc, const ushort* __restrict__ vct,
    ushort* __restrict__ o)
{
  __shared__ float  kt[64*32];       // 8 KB f32 kc tile
  __shared__ ushort vcT[32*72];      // 4.5 KB bf16 Vc^T tile [d][n], pad 8
  __shared__ ushort Pl[64*72];       // 9 KB bf16 P tile [tok][n], pad 8
  __shared__ float  ocl[64*36];      // 9 KB f32 final oc [tok][d], pad 4
  __shared__ float4 meta[4*64];      // 4 KB (l, best, bestn, -)   -> ~35 KB
  int e = blockIdx.x;
  int hh = e & 7;
  int b  = (e >> 3) & 3;
  int qq = (e >> 5) & 7;
  int r  = e >> 8;
  int g  = (r==0) ? (31-qq) : (r==1) ? qq : (r==2) ? (23-qq) : (8+qq);
  int tid = threadIdx.x;
  int w = tid >> 6, lane = tid & 63;
  const float*  kcg  = kc  + ((size_t)(b*NH + hh)*NB)*DH;
  const ushort* vctg = vct + ((size_t)(b*NH + hh)*DH)*NB;

  // ---- phase 1
  {
    int t = g*64 + lane;
    int own = t >> 2, nvis = (t+1) >> 2;
    int nmax = 16*(g+1);                  // block-uniform visibility bound
    float qv[32];
    {
      const float4* qr = (const float4*)(qk + ((size_t)b*SEQ + t)*QKS + hh*DH);
      #pragma unroll
      for (int d8=0; d8<8; d8++){
        float4 a4 = qr[d8];
        qv[4*d8]=a4.x; qv[4*d8+1]=a4.y; qv[4*d8+2]=a4.z; qv[4*d8+3]=a4.w;
      }
    }
    float l = 0.f, best = -1e30f;
    int bn1 = -1;
    float4v acc0 = (float4v){0.f,0.f,0.f,0.f};
    float4v acc1 = (float4v){0.f,0.f,0.f,0.f};

    int tiles = (g + 4) >> 2;             // ceil(16(g+1)/64)
    for (int ti=0; ti<tiles; ++ti){
      int base = ti*64;
      if (ti) __syncthreads();            // prev tile's MFMA reads done
      {                                   // stage kt (2 float4/thr) + vcT (1 uint4/thr, [d][n])
        const float4* sk = (const float4*)(kcg + (size_t)base*DH);
        ((float4*)kt)[tid]     = sk[tid];
        ((float4*)kt)[tid+256] = sk[tid+256];
        int sd = tid >> 3, sn = (tid & 7)*8;
        *(uint4*)&vcT[sd*72 + sn] = *(const uint4*)&vctg[(size_t)sd*NB + base + sn];
      }
      __syncthreads();
      // score phase: wave w owns rows [w*16, w*16+16)
      float ps[16];
      #pragma unroll
      for (int j=0; j<16; ++j){
        int rr = w*16 + j;
        int n = base + rr;
        float p = 0.f;
        if (n < nmax){                    // wave-uniform
          const float4* kp = (const float4*)&kt[rr*32];
          float s = 0.f;
          #pragma unroll
          for (int d8=0; d8<8; d8++){     // exact grouped-4 ordering: argmax-stable
            float4 k4 = kp[d8];
            s += qv[4*d8]*k4.x + qv[4*d8+1]*k4.y + qv[4*d8+2]*k4.z + qv[4*d8+3]*k4.w;
          }
          s *= SCALE;
          bool act = (n < nvis);
          if (act && n != own && s > best){ best = s; bn1 = n; }  // ascending n in-wave
          p = act ? __expf(s) : 0.f;      // max-free: |s| small, exp safe
          l += p;
        }
        ps[j] = p;
      }
      {                                   // P[lane][w*16..+16] as 2x b128
        uint4 u0, u1;
        u0.x = pk2(ps[0],ps[1]);  u0.y = pk2(ps[2],ps[3]);
        u0.z = pk2(ps[4],ps[5]);  u0.w = pk2(ps[6],ps[7]);
        u1.x = pk2(ps[8],ps[9]);  u1.y = pk2(ps[10],ps[11]);
        u1.z = pk2(ps[12],ps[13]);u1.w = pk2(ps[14],ps[15]);
        *(uint4*)&Pl[lane*72 + w*16]     = u0;
        *(uint4*)&Pl[lane*72 + w*16 + 8] = u1;
      }
      __syncthreads();                    // P complete
      // MFMA phase: wave w -> tokens [16w, 16w+16), full 64-n K via 2 ksteps
      #pragma unroll
      for (int ks=0; ks<2; ++ks){
        short8v a  = *(short8v*)&Pl [(16*w + (lane&15))*72 + ks*32 + (lane>>4)*8];
        short8v b0 = *(short8v*)&vcT[(lane&15)*72        + ks*32 + (lane>>4)*8];
        short8v b1 = *(short8v*)&vcT[((lane&15)+16)*72   + ks*32 + (lane>>4)*8];
        acc0 = __builtin_amdgcn_mfma_f32_16x16x32_bf16(a, b0, acc0, 0, 0, 0);
        acc1 = __builtin_amdgcn_mfma_f32_16x16x32_bf16(a, b1, acc1, 0, 0, 0);
      }
    }
    // write oc (f32) + meta
    #pragma unroll
    for (int r2=0; r2<4; ++r2){
      int token = 16*w + (lane>>4)*4 + r2;
      ocl[token*36 + (lane&15)]      = acc0[r2];
      ocl[token*36 + 16 + (lane&15)] = acc1[r2];
    }
    meta[w*64 + lane] = make_float4(l, best, __int_as_float(bn1), 0.f);
  }
  __syncthreads();

  // ---- phase 2: 4 lanes per token, d-split (8 dims per lane)
  {
    int tok = tid >> 2;
    int ds  = (tid & 3)*8;
    int t = g*64 + tok;
    int own = t >> 2, nvis = (t+1) >> 2;
    float q8[8];
    {
      const float4* qr = (const float4*)(qk + ((size_t)b*SEQ + t)*QKS + hh*DH + ds);
      float4 a4 = qr[0], b4 = qr[1];
      q8[0]=a4.x; q8[1]=a4.y; q8[2]=a4.z; q8[3]=a4.w;
      q8[4]=b4.x; q8[5]=b4.y; q8[6]=b4.z; q8[7]=b4.w;
    }
    float out8[8];
    {
      float4 oA = *(const float4*)&ocl[tok*36 + ds];
      float4 oB = *(const float4*)&ocl[tok*36 + ds + 4];
      out8[0]=oA.x; out8[1]=oA.y; out8[2]=oA.z; out8[3]=oA.w;
      out8[4]=oB.x; out8[5]=oB.y; out8[6]=oB.z; out8[7]=oB.w;
    }
    float ll = 0.f, bb = -1e30f;
    int bn = (own==0) ? 1 : 0;         // jax top_k fallback
    #pragma unroll
    for (int sp=0; sp<4; ++sp){
      float4 m4 = meta[sp*64 + tok];
      ll += m4.x;
      int mi = __float_as_int(m4.z);
      // equal scores resolve to the lower n (mi>=0 excludes empty partials)
      if (m4.y > bb || (m4.y == bb && mi >= 0 && mi < bn)){ bb = m4.y; bn = mi; }
    }
    const ushort* gr = vg + ((size_t)b*SEQ + t)*VGS + 256;
    float g0 = sigmoidf_(bf2f(gr[hh])), g1 = sigmoidf_(bf2f(gr[8+hh])), g2 = sigmoidf_(bf2f(gr[16+hh]));
    float inv = (nvis > 0) ? g0/ll : 0.f;
    #pragma unroll
    for (int j=0;j<8;j++) out8[j] *= inv;

    // selection branch: own block + best block, causal token mask, d-split dots
    const float*  kb2 = qk + (size_t)b*SEQ*QKS + 256 + hh*DH + ds;
    const ushort* vb2 = vg + (size_t)b*SEQ*VGS + hh*DH + ds;
    float s2[8];
    float m2 = -1e30f;
    #pragma unroll
    for (int ki=0; ki<8; ++ki){
      int tt = (ki<4 ? own : bn)*4 + (ki&3);
      float s = -1e30f;
      if (tt <= t){                       // uniform across the 4 lanes of this token
        const float4* kr = (const float4*)(kb2 + (size_t)tt*QKS);
        float4 a4 = kr[0], c4 = kr[1];
        float ps = q8[0]*a4.x + q8[1]*a4.y + q8[2]*a4.z + q8[3]*a4.w
                 + q8[4]*c4.x + q8[5]*c4.y + q8[6]*c4.z + q8[7]*c4.w;
        ps += __shfl_xor(ps, 1);
        ps += __shfl_xor(ps, 2);
        s = ps*SCALE;
        m2 = fmaxf(m2, s);
      }
      s2[ki] = s;
    }
    float l2 = 0.f;
    #pragma unroll
    for (int ki=0; ki<8; ++ki)
      if (s2[ki] > -1e29f) l2 += __expf(s2[ki] - m2);
    float inv2 = g1/l2;                   // l2 >= 1 (self token always visible)
    #pragma unroll
    for (int ki=0; ki<8; ++ki){
      int tt = (ki<4 ? own : bn)*4 + (ki&3);
      if (tt <= t){
        float pw = __expf(s2[ki] - m2) * inv2;
        uint4 u = *(const uint4*)(vb2 + (size_t)tt*VGS);
        float f[8]; bfu4_to_f32(u, f);
        #pragma unroll
        for (int j=0;j<8;j++) out8[j] += pw*f[j];
      }
    }

    // sliding window (W=2): tokens t-1, t
    int tp = (t>0) ? t-1 : 0;
    float sa, sb;
    {
      const float4* ka = (const float4*)(kb2 + (size_t)tp*QKS);
      const float4* kb4= (const float4*)(kb2 + (size_t)t *QKS);
      float4 a0 = ka[0], a1 = ka[1], b0 = kb4[0], b1 = kb4[1];
      float pa_ = q8[0]*a0.x + q8[1]*a0.y + q8[2]*a0.z + q8[3]*a0.w
                + q8[4]*a1.x + q8[5]*a1.y + q8[6]*a1.z + q8[7]*a1.w;
      float pb_ = q8[0]*b0.x + q8[1]*b0.y + q8[2]*b0.z + q8[3]*b0.w
                + q8[4]*b1.x + q8[5]*b1.y + q8[6]*b1.z + q8[7]*b1.w;
      pa_ += __shfl_xor(pa_, 1); pa_ += __shfl_xor(pa_, 2);
      pb_ += __shfl_xor(pb_, 1); pb_ += __shfl_xor(pb_, 2);
      sa = pa_*SCALE; sb = pb_*SCALE;
    }
    float m3 = (t>0) ? fmaxf(sa, sb) : sb;
    float pa = (t>0) ? __expf(sa-m3) : 0.f;
    float pb = __expf(sb-m3);
    float inv3 = g2/(pa+pb);
    float va[8], vbv[8];
    bfu4_to_f32(*(const uint4*)(vb2 + (size_t)tp*VGS), va);
    bfu4_to_f32(*(const uint4*)(vb2 + (size_t)t *VGS), vbv);
    ushort* orow = o + ((size_t)b*SEQ + t)*DIM + hh*DH + ds;
    float rr[8];
    #pragma unroll
    for (int j=0;j<8;j++) rr[j] = out8[j] + (pa*va[j] + pb*vbv[j])*inv3;
    uint4 u;
    u.x = pk2(rr[0], rr[1]);
    u.y = pk2(rr[2], rr[3]);
    u.z = pk2(rr[4], rr[5]);
    u.w = pk2(rr[6], rr[7]);
    *(uint4*)orow = u;
  }
}

extern "C" void kernel_launch(void* const* d_in, const int* in_sizes, int n_in,
                              void* d_out, int out_size, void* d_ws, size_t ws_size,
                              hipStream_t stream) {
  const float* x_in   = (const float*)d_in[0];
  const float* ln_a_g = (const float*)d_in[1];
  const float* ln_a_b = (const float*)d_in[2];
  const float* Wq     = (const float*)d_in[3];
  const float* Wk     = (const float*)d_in[4];
  const float* Wv     = (const float*)d_in[5];
  const float* Wg     = (const float*)d_in[6];
  const float* Wo     = (const float*)d_in[7];
  const float* ln_f_g = (const float*)d_in[8];
  const float* ln_f_b = (const float*)d_in[9];
  const float* W1     = (const float*)d_in[10];
  const float* b1     = (const float*)d_in[11];
  const float* W2     = (const float*)d_in[12];
  const float* b2     = (const float*)d_in[13];

  float* xout = (float*)d_out;             // running residual stream [8192][256] f32
  float* ws = (float*)d_ws;
  const size_t NTOK = (size_t)BATCH*SEQ;   // 8192
  float* h    = ws;                                    // [8192][256] f32
  float* qkb  = h    + NTOK*DIM;                       // [8192][512] f32
  float* kcb  = qkb  + NTOK*QKS;                       // [4][8][512][32] f32
  ushort* vctb = (ushort*)(kcb + (size_t)BATCH*NH*NB*DH);  // [4][8][32][512] bf16 (transposed)
  float* wqk  = (float*)(vctb + (size_t)BATCH*NH*NB*DH);   // [4][256][512] f32
  ushort* hb   = (ushort*)(wqk + (size_t)4*DIM*QKS);   // [8192][256] bf16
  ushort* vgu  = hb   + NTOK*DIM;                      // [8192][320] bf16
  ushort* obu  = vgu  + NTOK*VGS;                      // [8192][256] bf16
  ushort* midu = obu  + NTOK*DIM;                      // [8192][512] bf16
  ushort* wvgT = midu + NTOK*512;                      // [4][320][256] bf16
  ushort* woT  = wvgT + (size_t)4*VGS*DIM;             // [4][256][256] bf16
  ushort* w1T  = woT  + (size_t)4*DIM*DIM;             // [2][512][256] bf16
  ushort* w2T  = w1T  + (size_t)2*512*DIM;             // [2][256][512] bf16

  copy_f32<<<2048, 256, 0, stream>>>(x_in, xout, (int)(NTOK*DIM/4));
  build_wqk <<<(4*256*QKS+255)/256, 256, 0, stream>>>(Wq, Wk, wqk);
  build_wvgT<<<(4*VGS*256+255)/256, 256, 0, stream>>>(Wv, Wg, wvgT);
  build_wT  <<<(4*256*256+255)/256, 256, 0, stream>>>(Wo, woT, 4, 256, 256);
  build_wT  <<<(2*256*512+255)/256, 256, 0, stream>>>(W1, w1T, 2, 256, 512);
  build_wT  <<<(2*512*256+255)/256, 256, 0, stream>>>(W2, w2T, 2, 512, 256);

  dim3 gfused(64,13), g4(64,4), g8(64,8);
  for (int i=0;i<4;i++){
    ln_k<<<2048,256,0,stream>>>(xout, ln_a_g + i*DIM, ln_a_b + i*DIM, h, hb);
    gemm_qkvg<<<gfused,256,0,stream>>>(h, hb, wqk + (size_t)i*DIM*QKS, wvgT + (size_t)i*VGS*DIM,
                                       qkb, vgu, kcb, vctb);
    nsa_attn<<<1024,256,0,stream>>>(qkb, vgu, kcb, vctb, obu);
    gemm_bf16<false,false,true,false><<<g4,256,0,stream>>>(obu, woT + (size_t)i*DIM*DIM, nullptr, xout, 8192,DIM,256);
    if (i & 1){
      int l = i >> 1;
      ln_k<<<2048,256,0,stream>>>(xout, ln_f_g + l*DIM, ln_f_b + l*DIM, h, hb);
      gemm_bf16<true,true,false,true><<<g8,256,0,stream>>>(hb,   w1T + (size_t)l*512*DIM, b1 + l*512, midu, 8192,512,256);
      gemm_bf16<true,false,true,false><<<g4,256,0,stream>>>(midu, w2T + (size_t)l*DIM*512, b2 + l*DIM, xout, 8192,DIM,512);
    }
  }
}